// Round 1
// baseline (6773.301 us; speedup 1.0000x reference)
//
#include <hip/hip_runtime.h>
#include <hip/hip_bf16.h>
#include <math.h>

#define NH 16
#define DH 64
#define SEQ 2048
#define EMBED 1024
#define DINNER (NH * DH)   // 1024
#define BATCH 2
#define MTOK (BATCH * SEQ) // 4096 token rows

// ---------------------------------------------------------------------------
// Kernel 1: fused QKV projection.  C[m, n] = X[m, :] @ W[:, n] + b[n]
// blockIdx.z in {0,1,2} selects (Wq,bq,Q), (Wk,bk,K), (Wv,bv,V).
// Output written in [B, H, S, DH] layout for attention-friendly access.
// ---------------------------------------------------------------------------
__global__ __launch_bounds__(256) void qkv_proj(
    const float* __restrict__ X,
    const float* __restrict__ Wq, const float* __restrict__ Wk, const float* __restrict__ Wv,
    const float* __restrict__ bq, const float* __restrict__ bk, const float* __restrict__ bv,
    float* __restrict__ Q, float* __restrict__ K, float* __restrict__ V)
{
    const int which = blockIdx.z;
    const float* __restrict__ W   = (which == 0) ? Wq : (which == 1) ? Wk : Wv;
    const float* __restrict__ bia = (which == 0) ? bq : (which == 1) ? bk : bv;
    float* __restrict__ out       = (which == 0) ? Q  : (which == 1) ? K  : V;

    __shared__ float As[16][17];
    __shared__ float Bs[16][17];

    const int tx = threadIdx.x;      // 0..15
    const int ty = threadIdx.y;      // 0..15
    const int m = blockIdx.y * 16 + ty;   // token row, < 4096
    const int n = blockIdx.x * 16 + tx;   // inner dim col, < 1024

    float acc = 0.f;
    for (int k0 = 0; k0 < EMBED; k0 += 16) {
        As[ty][tx] = X[(size_t)m * EMBED + k0 + tx];
        Bs[ty][tx] = W[(size_t)(k0 + ty) * DINNER + n];
        __syncthreads();
#pragma unroll
        for (int kk = 0; kk < 16; ++kk)
            acc += As[ty][kk] * Bs[kk][tx];
        __syncthreads();
    }
    acc += bia[n];

    const int b = m / SEQ, s = m % SEQ;
    const int h = n >> 6,  d = n & 63;
    out[(((size_t)(b * NH + h) * SEQ) + s) * DH + d] = acc;
}

// ---------------------------------------------------------------------------
// Kernel 2: causal flash attention, fp32.
// 256 threads = 4 waves per block; each wave owns one query row.
// Lane d holds dimension d of q, acc; score via 64-lane butterfly reduce.
// Writes ctx in [B, S, H*DH] layout (transpose-on-write) for the out-proj GEMM.
// ---------------------------------------------------------------------------
__global__ __launch_bounds__(256) void attn_fwd(
    const float* __restrict__ Q, const float* __restrict__ K,
    const float* __restrict__ V, float* __restrict__ ctx)
{
    const int wave = threadIdx.x >> 6;
    const int lane = threadIdx.x & 63;
    const int qrow = blockIdx.x * 4 + wave;   // global row over B*H*S
    const int bh = qrow / SEQ;                // b*NH + h
    const int q  = qrow % SEQ;

    const float* __restrict__ Kb = K + (size_t)bh * SEQ * DH;
    const float* __restrict__ Vb = V + (size_t)bh * SEQ * DH;

    const float scale = 0.125f;  // 1/sqrt(64)
    float qd = Q[(size_t)qrow * DH + lane] * scale;

    float m_run = -INFINITY;
    float l_run = 0.f;
    float acc   = 0.f;

    for (int k = 0; k <= q; ++k) {
        float s = qd * Kb[(size_t)k * DH + lane];
        // butterfly sum across 64 lanes (all lanes end with the total)
#pragma unroll
        for (int off = 32; off; off >>= 1)
            s += __shfl_xor(s, off);

        float m_new = fmaxf(m_run, s);
        float corr  = __expf(m_run - m_new);   // exp(-inf)=0 on first iter
        float p     = __expf(s - m_new);
        l_run = l_run * corr + p;
        acc   = acc   * corr + p * Vb[(size_t)k * DH + lane];
        m_run = m_new;
    }
    acc /= l_run;

    const int b = bh >> 4;       // / NH
    const int h = bh & (NH - 1);
    ctx[((size_t)(b * SEQ + q) * NH + h) * DH + lane] = acc;
}

// ---------------------------------------------------------------------------
// Kernel 3: output projection.  out[m, n] = ctx[m, :] @ Wo[:, n] + bo[n]
// ---------------------------------------------------------------------------
__global__ __launch_bounds__(256) void out_proj(
    const float* __restrict__ ctx, const float* __restrict__ Wo,
    const float* __restrict__ bo, float* __restrict__ out)
{
    __shared__ float As[16][17];
    __shared__ float Bs[16][17];

    const int tx = threadIdx.x;
    const int ty = threadIdx.y;
    const int m = blockIdx.y * 16 + ty;
    const int n = blockIdx.x * 16 + tx;

    float acc = 0.f;
    for (int k0 = 0; k0 < DINNER; k0 += 16) {
        As[ty][tx] = ctx[(size_t)m * DINNER + k0 + tx];
        Bs[ty][tx] = Wo[(size_t)(k0 + ty) * EMBED + n];
        __syncthreads();
#pragma unroll
        for (int kk = 0; kk < 16; ++kk)
            acc += As[ty][kk] * Bs[kk][tx];
        __syncthreads();
    }
    out[(size_t)m * EMBED + n] = acc + bo[n];
}

// ---------------------------------------------------------------------------
extern "C" void kernel_launch(void* const* d_in, const int* in_sizes, int n_in,
                              void* d_out, int out_size, void* d_ws, size_t ws_size,
                              hipStream_t stream)
{
    const float* X  = (const float*)d_in[0];
    const float* Wq = (const float*)d_in[1];
    const float* bq = (const float*)d_in[2];
    const float* Wk = (const float*)d_in[3];
    const float* bk = (const float*)d_in[4];
    const float* Wv = (const float*)d_in[5];
    const float* bv = (const float*)d_in[6];
    const float* Wo = (const float*)d_in[7];
    const float* bo = (const float*)d_in[8];
    float* out = (float*)d_out;

    // workspace: Q | K | V | ctx, each B*H*S*DH = 4 Mi floats = 16 MB
    const size_t seg = (size_t)BATCH * NH * SEQ * DH;
    float* ws  = (float*)d_ws;
    float* Q   = ws;
    float* K   = ws + seg;
    float* V   = ws + 2 * seg;
    float* ctx = ws + 3 * seg;

    // 1) QKV projections
    {
        dim3 grid(DINNER / 16, MTOK / 16, 3);
        dim3 block(16, 16);
        qkv_proj<<<grid, block, 0, stream>>>(X, Wq, Wk, Wv, bq, bk, bv, Q, K, V);
    }
    // 2) causal attention
    {
        dim3 grid((BATCH * NH * SEQ) / 4);
        dim3 block(256);
        attn_fwd<<<grid, block, 0, stream>>>(Q, K, V, ctx);
    }
    // 3) output projection
    {
        dim3 grid(EMBED / 16, MTOK / 16);
        dim3 block(16, 16);
        out_proj<<<grid, block, 0, stream>>>(ctx, Wo, bo, out);
    }
}

// Round 2
// 225.024 us; speedup vs baseline: 30.1003x; 30.1003x over previous
//
#include <hip/hip_runtime.h>
#include <hip/hip_bf16.h>
#include <math.h>

#define NH 16
#define DH 64
#define SEQ 2048
#define EMBED 1024
#define DINNER 1024
#define BATCH 2
#define MTOK 4096   // BATCH*SEQ

typedef __bf16 bf16x8 __attribute__((ext_vector_type(8)));
typedef float  f32x4  __attribute__((ext_vector_type(4)));

// ---------------------------------------------------------------------------
// f32 -> bf16 flat convert (n divisible by 4)
// ---------------------------------------------------------------------------
__global__ __launch_bounds__(256) void cvt_bf16(
    const float* __restrict__ src, __bf16* __restrict__ dst, int n)
{
    int i = (blockIdx.x * 256 + threadIdx.x) * 4;
    if (i + 3 < n) {
        float4 v = *(const float4*)&src[i];
        dst[i + 0] = (__bf16)v.x;
        dst[i + 1] = (__bf16)v.y;
        dst[i + 2] = (__bf16)v.z;
        dst[i + 3] = (__bf16)v.w;
    }
}

// ---------------------------------------------------------------------------
// transpose + convert: src[R][C] f32 -> dst[C][R] bf16   (R,C multiples of 32)
// ---------------------------------------------------------------------------
__global__ __launch_bounds__(256) void tconv(
    const float* __restrict__ src, __bf16* __restrict__ dst, int R, int C)
{
    __shared__ float t[32][33];
    const int c0 = blockIdx.x * 32, r0 = blockIdx.y * 32;
    const int x = threadIdx.x & 31, y = threadIdx.x >> 5;   // 32 x 8
#pragma unroll
    for (int i = 0; i < 4; ++i)
        t[y + 8 * i][x] = src[(size_t)(r0 + y + 8 * i) * C + c0 + x];
    __syncthreads();
#pragma unroll
    for (int i = 0; i < 4; ++i)
        dst[(size_t)(c0 + y + 8 * i) * R + r0 + x] = (__bf16)t[x][y + 8 * i];
}

// ---------------------------------------------------------------------------
// bf16 MFMA GEMM, 128x128 tile, 4 waves (2x2), 16x16x32 MFMA, K-step 32.
// A[M][K] bf16, Bt[N][K] bf16 (pre-transposed weights).
// mode3=0: blockIdx.z selects Q/K/V epilogue; mode3=1: fp32 out[m][EMBED]+bias.
//   z=0 -> Q layout [bh][s][d] bf16, scaled by 0.125 (fold 1/sqrt(64))
//   z=1 -> K layout [bh][s][d] bf16
//   z=2 -> V layout transposed [bh][d][s] bf16
// ---------------------------------------------------------------------------
__global__ __launch_bounds__(256) void gemm128(
    const __bf16* __restrict__ A,
    const __bf16* __restrict__ Bt0, const __bf16* __restrict__ Bt1, const __bf16* __restrict__ Bt2,
    const float* __restrict__ b0, const float* __restrict__ b1, const float* __restrict__ b2,
    void* __restrict__ o0, void* __restrict__ o1, void* __restrict__ o2,
    int Kdim, int mode3)
{
    const int z = blockIdx.z;
    const __bf16* __restrict__ Bt = (z == 0) ? Bt0 : (z == 1) ? Bt1 : Bt2;
    const float*  __restrict__ bias = (z == 0) ? b0 : (z == 1) ? b1 : b2;
    void* __restrict__ outp = (z == 0) ? o0 : (z == 1) ? o1 : o2;
    const int mode = mode3 ? 3 : z;
    const float scale = (mode == 0) ? 0.125f : 1.0f;

    __shared__ __bf16 As[128][40];
    __shared__ __bf16 Bs[128][40];

    const int tid  = threadIdx.x;
    const int lane = tid & 63;
    const int wid  = tid >> 6;
    const int wm = wid >> 1, wn = wid & 1;
    const int ls = lane & 15, lg = lane >> 4;
    const int m0 = blockIdx.y * 128, n0 = blockIdx.x * 128;

    const int srow = tid >> 1;              // 0..127
    const int scol = (tid & 1) * 16;        // 0 or 16

    f32x4 acc[4][4] = {};

    for (int k0 = 0; k0 < Kdim; k0 += 32) {
        *(bf16x8*)&As[srow][scol]     = *(const bf16x8*)&A [(size_t)(m0 + srow) * Kdim + k0 + scol];
        *(bf16x8*)&As[srow][scol + 8] = *(const bf16x8*)&A [(size_t)(m0 + srow) * Kdim + k0 + scol + 8];
        *(bf16x8*)&Bs[srow][scol]     = *(const bf16x8*)&Bt[(size_t)(n0 + srow) * Kdim + k0 + scol];
        *(bf16x8*)&Bs[srow][scol + 8] = *(const bf16x8*)&Bt[(size_t)(n0 + srow) * Kdim + k0 + scol + 8];
        __syncthreads();

        bf16x8 af[4], bfr[4];
#pragma unroll
        for (int i = 0; i < 4; ++i) {
            af[i]  = *(const bf16x8*)&As[wm * 64 + i * 16 + ls][lg * 8];
            bfr[i] = *(const bf16x8*)&Bs[wn * 64 + i * 16 + ls][lg * 8];
        }
#pragma unroll
        for (int i = 0; i < 4; ++i)
#pragma unroll
            for (int jx = 0; jx < 4; ++jx)
                acc[i][jx] = __builtin_amdgcn_mfma_f32_16x16x32_bf16(af[i], bfr[jx], acc[i][jx], 0, 0, 0);
        __syncthreads();
    }

    // epilogue: C/D layout col = lane&15, row = (lane>>4)*4 + j   [m89-verified]
#pragma unroll
    for (int i = 0; i < 4; ++i) {
#pragma unroll
        for (int jx = 0; jx < 4; ++jx) {
#pragma unroll
            for (int j = 0; j < 4; ++j) {
                const int m = m0 + wm * 64 + i * 16 + lg * 4 + j;
                const int n = n0 + wn * 64 + jx * 16 + ls;
                const float v = (acc[i][jx][j] + bias[n]) * scale;
                if (mode == 3) {
                    ((float*)outp)[(size_t)m * EMBED + n] = v;
                } else {
                    const int b = m >> 11, s = m & 2047;   // SEQ=2048
                    const int h = n >> 6,  d = n & 63;
                    if (mode == 2)
                        ((__bf16*)outp)[(((size_t)(b * NH + h) * DH + d) << 11) + s] = (__bf16)v;
                    else
                        ((__bf16*)outp)[((((size_t)(b * NH + h) << 11) + s) * DH) + d] = (__bf16)v;
                }
            }
        }
    }
}

// ---------------------------------------------------------------------------
// MFMA causal flash attention. 1 wave per block, 16 query rows per block.
// Q,K: [bh][s][d] bf16 (Q pre-scaled by 1/8). Vt: [bh][d][s] bf16.
// Per 32-key tile: 4 MFMA (QK^T) + online softmax + LDS P round-trip + 4 MFMA (PV).
// ctx written bf16 [b*SEQ+s][h*64+d] for the out-proj GEMM.
// ---------------------------------------------------------------------------
__global__ __launch_bounds__(64) void attn_mfma(
    const __bf16* __restrict__ Q, const __bf16* __restrict__ K,
    const __bf16* __restrict__ Vt, __bf16* __restrict__ ctx)
{
    __shared__ __bf16 Plds[16][40];

    const int lane = threadIdx.x;
    const int ls = lane & 15, lg = lane >> 4;
    const int bh = blockIdx.x & 31;               // b*NH+h over 32
    const int qt = 127 - (blockIdx.x >> 5);       // reversed: long blocks first
    const int qb = qt * 16;
    const int b = bh >> 4, h = bh & 15;

    const __bf16* __restrict__ Qb = Q  + ((size_t)bh << 11) * DH;
    const __bf16* __restrict__ Kb = K  + ((size_t)bh << 11) * DH;
    const __bf16* __restrict__ Vb = Vt + ((size_t)bh << 11) * DH;  // bh*64*2048

    const bf16x8 aq0 = *(const bf16x8*)&Qb[(size_t)(qb + ls) * DH + lg * 8];
    const bf16x8 aq1 = *(const bf16x8*)&Qb[(size_t)(qb + ls) * DH + 32 + lg * 8];

    f32x4 o0 = {}, o1 = {}, o2 = {}, o3 = {};
    float mrun[4] = {-INFINITY, -INFINITY, -INFINITY, -INFINITY};
    float lrun[4] = {0.f, 0.f, 0.f, 0.f};

    const int ntiles = (qb + 16 + 31) >> 5;
    for (int t = 0; t < ntiles; ++t) {
        const int kb = t * 32;

        // ---- QK^T: S[16 q][32 k], two 16-key halves ----
        f32x4 s0 = {}, s1 = {};
        {
            const __bf16* kp = &Kb[(size_t)(kb + ls) * DH + lg * 8];
            s0 = __builtin_amdgcn_mfma_f32_16x16x32_bf16(aq0, *(const bf16x8*)kp,        s0, 0, 0, 0);
            s0 = __builtin_amdgcn_mfma_f32_16x16x32_bf16(aq1, *(const bf16x8*)(kp + 32), s0, 0, 0, 0);
        }
        {
            const __bf16* kp = &Kb[(size_t)(kb + 16 + ls) * DH + lg * 8];
            s1 = __builtin_amdgcn_mfma_f32_16x16x32_bf16(aq0, *(const bf16x8*)kp,        s1, 0, 0, 0);
            s1 = __builtin_amdgcn_mfma_f32_16x16x32_bf16(aq1, *(const bf16x8*)(kp + 32), s1, 0, 0, 0);
        }

        // ---- causal mask + online softmax (rows = qb+lg*4+j, cols = kb+{ls,16+ls}) ----
        const int q0 = qb + lg * 4;
        const int key0 = kb + ls, key1 = kb + 16 + ls;
#pragma unroll
        for (int j = 0; j < 4; ++j) {
            if (key0 > q0 + j) s0[j] = -INFINITY;
            if (key1 > q0 + j) s1[j] = -INFINITY;
            float tm = fmaxf(s0[j], s1[j]);
#pragma unroll
            for (int off = 1; off < 16; off <<= 1)
                tm = fmaxf(tm, __shfl_xor(tm, off));
            const float mn = fmaxf(mrun[j], tm);
            const float corr = __expf(mrun[j] - mn);
            mrun[j] = mn;
            const float p0 = __expf(s0[j] - mn);
            const float p1 = __expf(s1[j] - mn);
            float ts = p0 + p1;
#pragma unroll
            for (int off = 1; off < 16; off <<= 1)
                ts += __shfl_xor(ts, off);
            lrun[j] = lrun[j] * corr + ts;
            o0[j] *= corr; o1[j] *= corr; o2[j] *= corr; o3[j] *= corr;
            Plds[lg * 4 + j][ls]      = (__bf16)p0;
            Plds[lg * 4 + j][16 + ls] = (__bf16)p1;
        }
        __syncthreads();

        // ---- PV: O[16 q][64 d] += P[16][32] * V[32][64] ----
        const bf16x8 ap = *(const bf16x8*)&Plds[ls][lg * 8];
        o0 = __builtin_amdgcn_mfma_f32_16x16x32_bf16(ap, *(const bf16x8*)&Vb[(size_t)(0  + ls) * SEQ + kb + lg * 8], o0, 0, 0, 0);
        o1 = __builtin_amdgcn_mfma_f32_16x16x32_bf16(ap, *(const bf16x8*)&Vb[(size_t)(16 + ls) * SEQ + kb + lg * 8], o1, 0, 0, 0);
        o2 = __builtin_amdgcn_mfma_f32_16x16x32_bf16(ap, *(const bf16x8*)&Vb[(size_t)(32 + ls) * SEQ + kb + lg * 8], o2, 0, 0, 0);
        o3 = __builtin_amdgcn_mfma_f32_16x16x32_bf16(ap, *(const bf16x8*)&Vb[(size_t)(48 + ls) * SEQ + kb + lg * 8], o3, 0, 0, 0);
        __syncthreads();
    }

    // ---- epilogue: divide by l, write ctx [token][h*64+d] bf16 ----
#pragma unroll
    for (int j = 0; j < 4; ++j) {
        const float inv = 1.0f / lrun[j];
        const size_t base = ((size_t)(b * SEQ + qb + lg * 4 + j)) * DINNER + h * 64;
        ctx[base + 0  + ls] = (__bf16)(o0[j] * inv);
        ctx[base + 16 + ls] = (__bf16)(o1[j] * inv);
        ctx[base + 32 + ls] = (__bf16)(o2[j] * inv);
        ctx[base + 48 + ls] = (__bf16)(o3[j] * inv);
    }
}

// ---------------------------------------------------------------------------
extern "C" void kernel_launch(void* const* d_in, const int* in_sizes, int n_in,
                              void* d_out, int out_size, void* d_ws, size_t ws_size,
                              hipStream_t stream)
{
    const float* X  = (const float*)d_in[0];
    const float* Wq = (const float*)d_in[1];
    const float* bq = (const float*)d_in[2];
    const float* Wk = (const float*)d_in[3];
    const float* bk = (const float*)d_in[4];
    const float* Wv = (const float*)d_in[5];
    const float* bv = (const float*)d_in[6];
    const float* Wo = (const float*)d_in[7];
    const float* bo = (const float*)d_in[8];
    float* out = (float*)d_out;

    // bf16 workspace layout (element offsets, 1 Mi = 1048576)
    __bf16* ws  = (__bf16*)d_ws;
    const size_t MI = 1048576;
    __bf16* Xb   = ws;               // 4 Mi  [4096][1024]
    __bf16* Wtq  = ws + 4  * MI;     // 1 Mi  [1024 n][1024 k]
    __bf16* Wtk  = ws + 5  * MI;
    __bf16* Wtv  = ws + 6  * MI;
    __bf16* Wto  = ws + 7  * MI;
    __bf16* Qb   = ws + 8  * MI;     // 4 Mi  [bh][s][d], pre-scaled 1/8
    __bf16* Kb   = ws + 12 * MI;     // 4 Mi  [bh][s][d]
    __bf16* Vtb  = ws + 16 * MI;     // 4 Mi  [bh][d][s]
    __bf16* ctxb = ws + 20 * MI;     // 4 Mi  [tok][h*64+d]

    // 1) convert inputs/weights to bf16 (weights transposed to [N][K])
    cvt_bf16<<<dim3(MTOK * EMBED / 1024), dim3(256), 0, stream>>>(X, Xb, MTOK * EMBED);
    {
        dim3 g(EMBED / 32, EMBED / 32), blk(256);
        tconv<<<g, blk, 0, stream>>>(Wq, Wtq, EMBED, DINNER);
        tconv<<<g, blk, 0, stream>>>(Wk, Wtk, EMBED, DINNER);
        tconv<<<g, blk, 0, stream>>>(Wv, Wtv, EMBED, DINNER);
        tconv<<<g, blk, 0, stream>>>(Wo, Wto, DINNER, EMBED);
    }

    // 2) fused QKV projection (bf16 MFMA GEMM), writes Q(scaled)/K row-major + V transposed
    {
        dim3 grid(DINNER / 128, MTOK / 128, 3), blk(256);
        gemm128<<<grid, blk, 0, stream>>>(Xb, Wtq, Wtk, Wtv, bq, bk, bv,
                                          Qb, Kb, Vtb, EMBED, 0);
    }

    // 3) causal flash attention (MFMA)
    {
        dim3 grid(BATCH * NH * (SEQ / 16)), blk(64);
        attn_mfma<<<grid, blk, 0, stream>>>(Qb, Kb, Vtb, ctxb);
    }

    // 4) output projection -> fp32 d_out
    {
        dim3 grid(EMBED / 128, MTOK / 128, 1), blk(256);
        gemm128<<<grid, blk, 0, stream>>>(ctxb, Wto, Wto, Wto, bo, bo, bo,
                                          out, out, out, DINNER, 1);
    }
}

// Round 3
// 165.541 us; speedup vs baseline: 40.9161x; 1.3593x over previous
//
#include <hip/hip_runtime.h>
#include <hip/hip_bf16.h>
#include <math.h>

#define NH 16
#define DH 64
#define SEQ 2048
#define EMBED 1024
#define DINNER 1024
#define BATCH 2
#define MTOK 4096   // BATCH*SEQ

typedef __bf16 bf16x8 __attribute__((ext_vector_type(8)));
typedef float  f32x4  __attribute__((ext_vector_type(4)));
typedef float  f32x16 __attribute__((ext_vector_type(16)));
typedef unsigned int u32;

// async global->LDS, 16B per lane (dest = wave-uniform base + lane*16)
__device__ __forceinline__ void gload16(const void* g, void* l) {
    __builtin_amdgcn_global_load_lds((const __attribute__((address_space(1))) void*)g,
                                     (__attribute__((address_space(3))) void*)l, 16, 0, 0);
}

// ---------------------------------------------------------------------------
// f32 -> bf16 flat convert (n divisible by 4)
// ---------------------------------------------------------------------------
__global__ __launch_bounds__(256) void cvt_bf16(
    const float* __restrict__ src, __bf16* __restrict__ dst, int n)
{
    int i = (blockIdx.x * 256 + threadIdx.x) * 4;
    if (i + 3 < n) {
        float4 v = *(const float4*)&src[i];
        dst[i + 0] = (__bf16)v.x;
        dst[i + 1] = (__bf16)v.y;
        dst[i + 2] = (__bf16)v.z;
        dst[i + 3] = (__bf16)v.w;
    }
}

// ---------------------------------------------------------------------------
// transpose + convert: src[R][C] f32 -> dst[C][R] bf16   (R,C multiples of 32)
// ---------------------------------------------------------------------------
__global__ __launch_bounds__(256) void tconv(
    const float* __restrict__ src, __bf16* __restrict__ dst, int R, int C)
{
    __shared__ float t[32][33];
    const int c0 = blockIdx.x * 32, r0 = blockIdx.y * 32;
    const int x = threadIdx.x & 31, y = threadIdx.x >> 5;   // 32 x 8
#pragma unroll
    for (int i = 0; i < 4; ++i)
        t[y + 8 * i][x] = src[(size_t)(r0 + y + 8 * i) * C + c0 + x];
    __syncthreads();
#pragma unroll
    for (int i = 0; i < 4; ++i)
        dst[(size_t)(c0 + y + 8 * i) * R + r0 + x] = (__bf16)t[x][y + 8 * i];
}

// ---------------------------------------------------------------------------
// bf16 MFMA GEMM, 128x128 tile, 4 waves (2x2), 16x16x32 MFMA, K-step 32.
// m97 recipe: linear [128][32] LDS staged via global_load_lds width=16.
// A[M][K] bf16, Bt[N][K] bf16 (pre-transposed weights).
// mode3=0: blockIdx.z selects Q/K/V epilogue; mode3=1: fp32 out[m][EMBED]+bias.
// ---------------------------------------------------------------------------
__global__ __launch_bounds__(256) void gemm128(
    const __bf16* __restrict__ A,
    const __bf16* __restrict__ Bt0, const __bf16* __restrict__ Bt1, const __bf16* __restrict__ Bt2,
    const float* __restrict__ b0, const float* __restrict__ b1, const float* __restrict__ b2,
    void* __restrict__ o0, void* __restrict__ o1, void* __restrict__ o2,
    int Kdim, int mode3)
{
    const int z = blockIdx.z;
    const __bf16* __restrict__ Bt = (z == 0) ? Bt0 : (z == 1) ? Bt1 : Bt2;
    const float*  __restrict__ bias = (z == 0) ? b0 : (z == 1) ? b1 : b2;
    void* __restrict__ outp = (z == 0) ? o0 : (z == 1) ? o1 : o2;
    const int mode = mode3 ? 3 : z;
    const float scale = (mode == 0) ? 0.125f : 1.0f;

    __shared__ __bf16 As[128 * 32];
    __shared__ __bf16 Bs[128 * 32];

    const int tid  = threadIdx.x;
    const int lane = tid & 63;
    const int wid  = tid >> 6;
    const int wm = wid >> 1, wn = wid & 1;
    const int ls = lane & 15, lg = lane >> 4;
    const int m0 = blockIdx.y * 128, n0 = blockIdx.x * 128;

    const int sr = tid >> 2;           // 0..63
    const int sc = (tid & 3) * 8;      // element col offset (8 bf16 = 16B)

    f32x4 acc[4][4] = {};

    for (int k0 = 0; k0 < Kdim; k0 += 32) {
        gload16(&A [(size_t)(m0 + sr)      * Kdim + k0 + sc], &As[sr * 32 + sc]);
        gload16(&A [(size_t)(m0 + 64 + sr) * Kdim + k0 + sc], &As[(64 + sr) * 32 + sc]);
        gload16(&Bt[(size_t)(n0 + sr)      * Kdim + k0 + sc], &Bs[sr * 32 + sc]);
        gload16(&Bt[(size_t)(n0 + 64 + sr) * Kdim + k0 + sc], &Bs[(64 + sr) * 32 + sc]);
        __syncthreads();

        bf16x8 af[4], bfr[4];
#pragma unroll
        for (int i = 0; i < 4; ++i) {
            af[i]  = *(const bf16x8*)&As[(wm * 64 + i * 16 + ls) * 32 + lg * 8];
            bfr[i] = *(const bf16x8*)&Bs[(wn * 64 + i * 16 + ls) * 32 + lg * 8];
        }
#pragma unroll
        for (int i = 0; i < 4; ++i)
#pragma unroll
            for (int jx = 0; jx < 4; ++jx)
                acc[i][jx] = __builtin_amdgcn_mfma_f32_16x16x32_bf16(af[i], bfr[jx], acc[i][jx], 0, 0, 0);
        __syncthreads();
    }

    // epilogue: C/D layout col = lane&15, row = (lane>>4)*4 + j   [m89-verified]
#pragma unroll
    for (int i = 0; i < 4; ++i) {
#pragma unroll
        for (int jx = 0; jx < 4; ++jx) {
#pragma unroll
            for (int j = 0; j < 4; ++j) {
                const int m = m0 + wm * 64 + i * 16 + lg * 4 + j;
                const int n = n0 + wn * 64 + jx * 16 + ls;
                const float v = (acc[i][jx][j] + bias[n]) * scale;
                if (mode == 3) {
                    ((float*)outp)[(size_t)m * EMBED + n] = v;
                } else {
                    const int b = m >> 11, s = m & 2047;   // SEQ=2048
                    const int h = n >> 6,  d = n & 63;
                    if (mode == 2)
                        ((__bf16*)outp)[(((size_t)(b * NH + h) * DH + d) << 11) + s] = (__bf16)v;
                    else
                        ((__bf16*)outp)[((((size_t)(b * NH + h) << 11) + s) * DH) + d] = (__bf16)v;
                }
            }
        }
    }
}

// ---------------------------------------------------------------------------
// MFMA causal flash attention, 32x32 MFMA, fully in-register (no LDS).
// 1 wave per block, 32 query rows. Swapped QK^T: S^T = K_tile @ Q_tile^T so
// each lane owns one q-column (col=lane&31) with 16 k-scores; partner lane
// (lane^32) holds the other 16. Softmax: in-lane tree + 1 shfl_xor(32).
// P -> bf16 PV B-frag via v_cvt_pk_bf16_f32 + v_permlane32_swap_b32 (T12).
// Q,K: [bh][s][d] bf16 (Q pre-scaled 1/8). Vt: [bh][d][s] bf16.
// ctx written bf16 [b*SEQ+s][h*64+d].
// ---------------------------------------------------------------------------
__global__ __launch_bounds__(64) void attn_mfma(
    const __bf16* __restrict__ Q, const __bf16* __restrict__ K,
    const __bf16* __restrict__ Vt, __bf16* __restrict__ ctx)
{
    const int lane = threadIdx.x & 63;
    const int col  = lane & 31;          // q within tile / A-row index
    const int hi   = lane >> 5;
    const int bh = blockIdx.x & 31;      // same-bh blocks stride 32 -> same XCD
    const int qt = 63 - (blockIdx.x >> 5);  // reversed: long blocks first
    const int qb = qt * 32;
    const int b = bh >> 4, h = bh & 15;

    const __bf16* __restrict__ Qb = Q  + ((size_t)bh << 11) * DH;
    const __bf16* __restrict__ Kb = K  + ((size_t)bh << 11) * DH;
    const __bf16* __restrict__ Vb = Vt + ((size_t)bh << 11) * DH;

    // Q B-frags (col = q, k-dim = d): contiguous bf16x8 per 16-d chunk
    bf16x8 qf[4], kf[4];
#pragma unroll
    for (int c = 0; c < 4; ++c) {
        qf[c] = *(const bf16x8*)&Qb[(size_t)(qb + col) * DH + c * 16 + hi * 8];
        kf[c] = *(const bf16x8*)&Kb[(size_t)col * DH + c * 16 + hi * 8];
    }

    f32x16 oT0 = {}, oT1 = {};           // O^T[d][q], d-halves 0-31 / 32-63
    float mrun = -INFINITY, lrun = 0.f;

    for (int t = 0; t <= qt; ++t) {
        const int kb = t * 32;

        // ---- QK^T: S^T[32k][32q] ----
        f32x16 st = {};
#pragma unroll
        for (int c = 0; c < 4; ++c)
            st = __builtin_amdgcn_mfma_f32_32x32x16_bf16(kf[c], qf[c], st, 0, 0, 0);

        // prefetch next K tile (reads past head end are benign: still in ws)
        bf16x8 kn[4];
#pragma unroll
        for (int c = 0; c < 4; ++c)
            kn[c] = *(const bf16x8*)&Kb[(size_t)(kb + 32 + col) * DH + c * 16 + hi * 8];

        // V A-frags for this tile (in flight during softmax)
        bf16x8 vf[2][2];
#pragma unroll
        for (int dh = 0; dh < 2; ++dh)
#pragma unroll
            for (int c = 0; c < 2; ++c)
                vf[dh][c] = *(const bf16x8*)&Vb[(size_t)(dh * 32 + col) * SEQ + kb + c * 16 + hi * 8];

        // ---- causal mask (diagonal tile only; row = k, col = q) ----
        if (t == qt) {
#pragma unroll
            for (int r = 0; r < 16; ++r) {
                const int row = (r & 3) + 8 * (r >> 2) + 4 * hi;
                if (row > col) st[r] = -INFINITY;
            }
        }

        // ---- online softmax, per q-column ----
        float t0 = fmaxf(fmaxf(fmaxf(st[0], st[1]), fmaxf(st[2], st[3])),
                         fmaxf(fmaxf(st[4], st[5]), fmaxf(st[6], st[7])));
        float t1 = fmaxf(fmaxf(fmaxf(st[8], st[9]),  fmaxf(st[10], st[11])),
                         fmaxf(fmaxf(st[12], st[13]), fmaxf(st[14], st[15])));
        float tmax = fmaxf(t0, t1);
        tmax = fmaxf(tmax, __shfl_xor(tmax, 32));
        const float mnew = fmaxf(mrun, tmax);
        const float corr = __expf(mrun - mnew);
        mrun = mnew;

        float p[16];
#pragma unroll
        for (int r = 0; r < 16; ++r) p[r] = __expf(st[r] - mnew);
        float ps0 = ((p[0] + p[1]) + (p[2] + p[3])) + ((p[4] + p[5]) + (p[6] + p[7]));
        float ps1 = ((p[8] + p[9]) + (p[10] + p[11])) + ((p[12] + p[13]) + (p[14] + p[15]));
        float psum = ps0 + ps1;
        psum += __shfl_xor(psum, 32);
        lrun = lrun * corr + psum;
        oT0 *= corr;
        oT1 *= corr;

        // ---- pack P -> bf16 B-frags (cvt_pk + permlane32_swap) ----
        // reg r holds k = (r&3) + 8*(r>>2) + 4*hi; word i = pk(p[2i], p[2i+1])
        u32 w[8];
#pragma unroll
        for (int i = 0; i < 8; ++i) {
            u32 r_;
            asm("v_cvt_pk_bf16_f32 %0, %1, %2" : "=v"(r_) : "v"(p[2 * i]), "v"(p[2 * i + 1]));
            w[i] = r_;
        }
        // chunk0 (k 0..15): {w0,w1,w2,w3}; chunk1 (k 16..31): {w4,w5,w6,w7}
        asm("v_permlane32_swap_b32 %0, %1" : "+v"(w[0]), "+v"(w[2]));
        asm("v_permlane32_swap_b32 %0, %1" : "+v"(w[1]), "+v"(w[3]));
        asm("v_permlane32_swap_b32 %0, %1" : "+v"(w[4]), "+v"(w[6]));
        asm("v_permlane32_swap_b32 %0, %1" : "+v"(w[5]), "+v"(w[7]));

        union { u32 u[4]; bf16x8 v; } c0_, c1_;
        c0_.u[0] = w[0]; c0_.u[1] = w[1]; c0_.u[2] = w[2]; c0_.u[3] = w[3];
        c1_.u[0] = w[4]; c1_.u[1] = w[5]; c1_.u[2] = w[6]; c1_.u[3] = w[7];

        // ---- PV: O^T[d][q] += V^T[d][k] P^T[k][q] ----
        oT0 = __builtin_amdgcn_mfma_f32_32x32x16_bf16(vf[0][0], c0_.v, oT0, 0, 0, 0);
        oT0 = __builtin_amdgcn_mfma_f32_32x32x16_bf16(vf[0][1], c1_.v, oT0, 0, 0, 0);
        oT1 = __builtin_amdgcn_mfma_f32_32x32x16_bf16(vf[1][0], c0_.v, oT1, 0, 0, 0);
        oT1 = __builtin_amdgcn_mfma_f32_32x32x16_bf16(vf[1][1], c1_.v, oT1, 0, 0, 0);

#pragma unroll
        for (int c = 0; c < 4; ++c) kf[c] = kn[c];
    }

    // ---- epilogue: O[q][d] = O^T/l -> ctx[token][h*64+d], 8B packed stores ----
    const float inv = 1.0f / lrun;
    const size_t base = ((size_t)(b * SEQ + qb + col)) * DINNER + h * 64;
#pragma unroll
    for (int g = 0; g < 4; ++g) {
        __bf16 t4[4];
#pragma unroll
        for (int j = 0; j < 4; ++j) t4[j] = (__bf16)(oT0[4 * g + j] * inv);
        *(uint2*)&ctx[base + 8 * g + 4 * hi] = *(uint2*)t4;
#pragma unroll
        for (int j = 0; j < 4; ++j) t4[j] = (__bf16)(oT1[4 * g + j] * inv);
        *(uint2*)&ctx[base + 32 + 8 * g + 4 * hi] = *(uint2*)t4;
    }
}

// ---------------------------------------------------------------------------
extern "C" void kernel_launch(void* const* d_in, const int* in_sizes, int n_in,
                              void* d_out, int out_size, void* d_ws, size_t ws_size,
                              hipStream_t stream)
{
    const float* X  = (const float*)d_in[0];
    const float* Wq = (const float*)d_in[1];
    const float* bq = (const float*)d_in[2];
    const float* Wk = (const float*)d_in[3];
    const float* bk = (const float*)d_in[4];
    const float* Wv = (const float*)d_in[5];
    const float* bv = (const float*)d_in[6];
    const float* Wo = (const float*)d_in[7];
    const float* bo = (const float*)d_in[8];
    float* out = (float*)d_out;

    // bf16 workspace layout (element offsets, 1 Mi = 1048576)
    __bf16* ws  = (__bf16*)d_ws;
    const size_t MI = 1048576;
    __bf16* Xb   = ws;               // 4 Mi  [4096][1024]
    __bf16* Wtq  = ws + 4  * MI;     // 1 Mi  [1024 n][1024 k]
    __bf16* Wtk  = ws + 5  * MI;
    __bf16* Wtv  = ws + 6  * MI;
    __bf16* Wto  = ws + 7  * MI;
    __bf16* Qb   = ws + 8  * MI;     // 4 Mi  [bh][s][d], pre-scaled 1/8
    __bf16* Kb   = ws + 12 * MI;     // 4 Mi  [bh][s][d]
    __bf16* Vtb  = ws + 16 * MI;     // 4 Mi  [bh][d][s]
    __bf16* ctxb = ws + 20 * MI;     // 4 Mi  [tok][h*64+d]

    // 1) convert inputs/weights to bf16 (weights transposed to [N][K])
    cvt_bf16<<<dim3(MTOK * EMBED / 1024), dim3(256), 0, stream>>>(X, Xb, MTOK * EMBED);
    {
        dim3 g(EMBED / 32, EMBED / 32), blk(256);
        tconv<<<g, blk, 0, stream>>>(Wq, Wtq, EMBED, DINNER);
        tconv<<<g, blk, 0, stream>>>(Wk, Wtk, EMBED, DINNER);
        tconv<<<g, blk, 0, stream>>>(Wv, Wtv, EMBED, DINNER);
        tconv<<<g, blk, 0, stream>>>(Wo, Wto, DINNER, EMBED);
    }

    // 2) fused QKV projection (bf16 MFMA GEMM), writes Q(scaled)/K row-major + V transposed
    {
        dim3 grid(DINNER / 128, MTOK / 128, 3), blk(256);
        gemm128<<<grid, blk, 0, stream>>>(Xb, Wtq, Wtk, Wtv, bq, bk, bv,
                                          Qb, Kb, Vtb, EMBED, 0);
    }

    // 3) causal flash attention (MFMA, in-register softmax)
    {
        dim3 grid(32 * (SEQ / 32)), blk(64);
        attn_mfma<<<grid, blk, 0, stream>>>(Qb, Kb, Vtb, ctxb);
    }

    // 4) output projection -> fp32 d_out
    {
        dim3 grid(EMBED / 128, MTOK / 128, 1), blk(256);
        gemm128<<<grid, blk, 0, stream>>>(ctxb, Wto, Wto, Wto, bo, bo, bo,
                                          out, out, out, DINNER, 1);
    }
}

// Round 4
// 159.356 us; speedup vs baseline: 42.5042x; 1.0388x over previous
//
#include <hip/hip_runtime.h>
#include <hip/hip_bf16.h>
#include <math.h>

#define NH 16
#define DH 64
#define SEQ 2048
#define EMBED 1024
#define DINNER 1024
#define BATCH 2
#define MTOK 4096   // BATCH*SEQ

typedef __bf16 bf16x8 __attribute__((ext_vector_type(8)));
typedef float  f32x4  __attribute__((ext_vector_type(4)));
typedef float  f32x16 __attribute__((ext_vector_type(16)));
typedef unsigned int u32;

// async global->LDS, 16B per lane (dest = wave-uniform base + lane*16)
__device__ __forceinline__ void gload16(const void* g, void* l) {
    __builtin_amdgcn_global_load_lds((const __attribute__((address_space(1))) void*)g,
                                     (__attribute__((address_space(3))) void*)l, 16, 0, 0);
}

// ---------------------------------------------------------------------------
// f32 -> bf16 flat convert (n divisible by 4)
// ---------------------------------------------------------------------------
__global__ __launch_bounds__(256) void cvt_bf16(
    const float* __restrict__ src, __bf16* __restrict__ dst, int n)
{
    int i = (blockIdx.x * 256 + threadIdx.x) * 4;
    if (i + 3 < n) {
        float4 v = *(const float4*)&src[i];
        dst[i + 0] = (__bf16)v.x;
        dst[i + 1] = (__bf16)v.y;
        dst[i + 2] = (__bf16)v.z;
        dst[i + 3] = (__bf16)v.w;
    }
}

// ---------------------------------------------------------------------------
// 4 weight transposes (all 1024x1024) in one launch: src[R][C] f32 -> dst[C][R] bf16
// ---------------------------------------------------------------------------
__global__ __launch_bounds__(256) void tconv4(
    const float* __restrict__ W0, const float* __restrict__ W1,
    const float* __restrict__ W2, const float* __restrict__ W3,
    __bf16* __restrict__ D0, __bf16* __restrict__ D1,
    __bf16* __restrict__ D2, __bf16* __restrict__ D3)
{
    const int z = blockIdx.z;
    const float* __restrict__ src = (z == 0) ? W0 : (z == 1) ? W1 : (z == 2) ? W2 : W3;
    __bf16* __restrict__ dst      = (z == 0) ? D0 : (z == 1) ? D1 : (z == 2) ? D2 : D3;
    const int R = 1024, C = 1024;

    __shared__ float t[32][33];
    const int c0 = blockIdx.x * 32, r0 = blockIdx.y * 32;
    const int x = threadIdx.x & 31, y = threadIdx.x >> 5;   // 32 x 8
#pragma unroll
    for (int i = 0; i < 4; ++i)
        t[y + 8 * i][x] = src[(size_t)(r0 + y + 8 * i) * C + c0 + x];
    __syncthreads();
#pragma unroll
    for (int i = 0; i < 4; ++i)
        dst[(size_t)(c0 + y + 8 * i) * R + r0 + x] = (__bf16)t[x][y + 8 * i];
}

// ---------------------------------------------------------------------------
// bf16 MFMA GEMM, 128x128 tile, 4 waves (2x2), 16x16x32 MFMA, K-step 32.
// m97 recipe: linear [128][32] LDS staged via global_load_lds width=16.
// A[M][K] bf16, Bt[N][K] bf16 (pre-transposed weights).
// mode3=0: blockIdx.z selects Q/K/V epilogue; mode3=1: fp32 out[m][EMBED]+bias.
//   z=0 -> Q layout [bh][s][d] bf16, scaled by 0.125*log2e (exp2-domain softmax)
//   z=1 -> K layout [bh][s][d] bf16
//   z=2 -> V layout transposed [bh][d][s] bf16
// ---------------------------------------------------------------------------
#define QSCALE 0.18033688f   // 0.125 * log2(e)

__global__ __launch_bounds__(256) void gemm128(
    const __bf16* __restrict__ A,
    const __bf16* __restrict__ Bt0, const __bf16* __restrict__ Bt1, const __bf16* __restrict__ Bt2,
    const float* __restrict__ b0, const float* __restrict__ b1, const float* __restrict__ b2,
    void* __restrict__ o0, void* __restrict__ o1, void* __restrict__ o2,
    int Kdim, int mode3)
{
    const int z = blockIdx.z;
    const __bf16* __restrict__ Bt = (z == 0) ? Bt0 : (z == 1) ? Bt1 : Bt2;
    const float*  __restrict__ bias = (z == 0) ? b0 : (z == 1) ? b1 : b2;
    void* __restrict__ outp = (z == 0) ? o0 : (z == 1) ? o1 : o2;
    const int mode = mode3 ? 3 : z;
    const float scale = (mode == 0) ? QSCALE : 1.0f;

    __shared__ __bf16 As[128 * 32];
    __shared__ __bf16 Bs[128 * 32];

    const int tid  = threadIdx.x;
    const int lane = tid & 63;
    const int wid  = tid >> 6;
    const int wm = wid >> 1, wn = wid & 1;
    const int ls = lane & 15, lg = lane >> 4;
    const int m0 = blockIdx.y * 128, n0 = blockIdx.x * 128;

    const int sr = tid >> 2;           // 0..63
    const int sc = (tid & 3) * 8;      // element col offset (8 bf16 = 16B)

    f32x4 acc[4][4] = {};

    for (int k0 = 0; k0 < Kdim; k0 += 32) {
        gload16(&A [(size_t)(m0 + sr)      * Kdim + k0 + sc], &As[sr * 32 + sc]);
        gload16(&A [(size_t)(m0 + 64 + sr) * Kdim + k0 + sc], &As[(64 + sr) * 32 + sc]);
        gload16(&Bt[(size_t)(n0 + sr)      * Kdim + k0 + sc], &Bs[sr * 32 + sc]);
        gload16(&Bt[(size_t)(n0 + 64 + sr) * Kdim + k0 + sc], &Bs[(64 + sr) * 32 + sc]);
        __syncthreads();

        bf16x8 af[4], bfr[4];
#pragma unroll
        for (int i = 0; i < 4; ++i) {
            af[i]  = *(const bf16x8*)&As[(wm * 64 + i * 16 + ls) * 32 + lg * 8];
            bfr[i] = *(const bf16x8*)&Bs[(wn * 64 + i * 16 + ls) * 32 + lg * 8];
        }
#pragma unroll
        for (int i = 0; i < 4; ++i)
#pragma unroll
            for (int jx = 0; jx < 4; ++jx)
                acc[i][jx] = __builtin_amdgcn_mfma_f32_16x16x32_bf16(af[i], bfr[jx], acc[i][jx], 0, 0, 0);
        __syncthreads();
    }

    // epilogue: C/D layout col = lane&15, row = (lane>>4)*4 + j   [m89-verified]
#pragma unroll
    for (int i = 0; i < 4; ++i) {
#pragma unroll
        for (int jx = 0; jx < 4; ++jx) {
#pragma unroll
            for (int j = 0; j < 4; ++j) {
                const int m = m0 + wm * 64 + i * 16 + lg * 4 + j;
                const int n = n0 + wn * 64 + jx * 16 + ls;
                const float v = (acc[i][jx][j] + bias[n]) * scale;
                if (mode == 3) {
                    ((float*)outp)[(size_t)m * EMBED + n] = v;
                } else {
                    const int b = m >> 11, s = m & 2047;   // SEQ=2048
                    const int h = n >> 6,  d = n & 63;
                    if (mode == 2)
                        ((__bf16*)outp)[(((size_t)(b * NH + h) * DH + d) << 11) + s] = (__bf16)v;
                    else
                        ((__bf16*)outp)[((((size_t)(b * NH + h) << 11) + s) * DH) + d] = (__bf16)v;
                }
            }
        }
    }
}

// ---------------------------------------------------------------------------
// MFMA causal flash attention, 32x32 MFMA, in-register softmax, 4-way k-split.
// Block = 256 threads = 4 waves, all on ONE q-tile (32 rows). Wave w handles
// k-tiles t = w, w+4, ... with an independent online softmax (exp2 domain,
// Q pre-scaled by 0.125*log2e), then waves merge (m,l,O) through LDS.
// Swapped QK^T: S^T = K_tile @ Q_tile^T; lane owns q-column col=lane&31.
// P -> bf16 PV B-frag via v_cvt_pk_bf16_f32 + v_permlane32_swap_b32 (T12).
// Defer-max (T13): skip O/l rescale unless tmax > mrun + 8 (p <= 2^8).
// Q,K: [bh][s][d] bf16. Vt: [bh][d][s] bf16. ctx: bf16 [b*SEQ+s][h*64+d].
// ---------------------------------------------------------------------------
__global__ __launch_bounds__(256) void attn_mfma(
    const __bf16* __restrict__ Q, const __bf16* __restrict__ K,
    const __bf16* __restrict__ Vt, __bf16* __restrict__ ctx)
{
    __shared__ float sO[3][32][64];   // [srcwave-1][reg][lane], conflict-free
    __shared__ float sm[3][64];
    __shared__ float sl[3][64];

    const int tid  = threadIdx.x;
    const int wave = tid >> 6;
    const int lane = tid & 63;
    const int col  = lane & 31;          // q within tile
    const int hi   = lane >> 5;
    const int bh = blockIdx.x & 31;      // consecutive blocks spread bh across XCDs
    const int qt = 63 - (blockIdx.x >> 5);  // reversed: long blocks first
    const int qb = qt * 32;
    const int b = bh >> 4, h = bh & 15;

    const __bf16* __restrict__ Qb = Q  + ((size_t)bh << 11) * DH;
    const __bf16* __restrict__ Kb = K  + ((size_t)bh << 11) * DH;
    const __bf16* __restrict__ Vb = Vt + ((size_t)bh << 11) * DH;

    // Q B-frags (col = q, k-dim = d)
    bf16x8 qf[4];
#pragma unroll
    for (int c = 0; c < 4; ++c)
        qf[c] = *(const bf16x8*)&Qb[(size_t)(qb + col) * DH + c * 16 + hi * 8];

    f32x16 oT0 = {}, oT1 = {};           // O^T[d][q], d-halves 0-31 / 32-63
    float mrun = -INFINITY, lrun = 0.f;

    bf16x8 kf[4];
    if (wave <= qt) {
#pragma unroll
        for (int c = 0; c < 4; ++c)
            kf[c] = *(const bf16x8*)&Kb[(size_t)(wave * 32 + col) * DH + c * 16 + hi * 8];
    }

    for (int t = wave; t <= qt; t += 4) {
        const int kb = t * 32;

        // ---- QK^T: S^T[32k][32q] ----
        f32x16 st = {};
#pragma unroll
        for (int c = 0; c < 4; ++c)
            st = __builtin_amdgcn_mfma_f32_32x32x16_bf16(kf[c], qf[c], st, 0, 0, 0);

        // prefetch this wave's next K tile (t+4); reads stay inside ws
        bf16x8 kn[4];
#pragma unroll
        for (int c = 0; c < 4; ++c)
            kn[c] = *(const bf16x8*)&Kb[(size_t)(kb + 128 + col) * DH + c * 16 + hi * 8];

        // V A-frags for this tile (in flight during softmax)
        bf16x8 vf[2][2];
#pragma unroll
        for (int dh = 0; dh < 2; ++dh)
#pragma unroll
            for (int c = 0; c < 2; ++c)
                vf[dh][c] = *(const bf16x8*)&Vb[(size_t)(dh * 32 + col) * SEQ + kb + c * 16 + hi * 8];

        // ---- causal mask (diagonal tile only; row = k, col = q) ----
        if (t == qt) {
#pragma unroll
            for (int r = 0; r < 16; ++r) {
                const int row = (r & 3) + 8 * (r >> 2) + 4 * hi;
                if (row > col) st[r] = -INFINITY;
            }
        }

        // ---- online softmax (exp2 domain), defer-max rescale ----
        float t0 = fmaxf(fmaxf(fmaxf(st[0], st[1]), fmaxf(st[2], st[3])),
                         fmaxf(fmaxf(st[4], st[5]), fmaxf(st[6], st[7])));
        float t1 = fmaxf(fmaxf(fmaxf(st[8], st[9]),  fmaxf(st[10], st[11])),
                         fmaxf(fmaxf(st[12], st[13]), fmaxf(st[14], st[15])));
        float tmax = fmaxf(t0, t1);
        tmax = fmaxf(tmax, __shfl_xor(tmax, 32));

        if (__any(tmax > mrun + 8.f)) {
            const float mnew = fmaxf(mrun, tmax);
            const float corr = exp2f(mrun - mnew);
            lrun *= corr;
            oT0 *= corr;
            oT1 *= corr;
            mrun = mnew;
        }

        float p[16];
#pragma unroll
        for (int r = 0; r < 16; ++r) p[r] = exp2f(st[r] - mrun);
        float ps0 = ((p[0] + p[1]) + (p[2] + p[3])) + ((p[4] + p[5]) + (p[6] + p[7]));
        float ps1 = ((p[8] + p[9]) + (p[10] + p[11])) + ((p[12] + p[13]) + (p[14] + p[15]));
        float psum = ps0 + ps1;
        psum += __shfl_xor(psum, 32);
        lrun += psum;

        // ---- pack P -> bf16 B-frags (cvt_pk + permlane32_swap) ----
        u32 w_[8];
#pragma unroll
        for (int i = 0; i < 8; ++i) {
            u32 r_;
            asm("v_cvt_pk_bf16_f32 %0, %1, %2" : "=v"(r_) : "v"(p[2 * i]), "v"(p[2 * i + 1]));
            w_[i] = r_;
        }
        asm("v_permlane32_swap_b32 %0, %1" : "+v"(w_[0]), "+v"(w_[2]));
        asm("v_permlane32_swap_b32 %0, %1" : "+v"(w_[1]), "+v"(w_[3]));
        asm("v_permlane32_swap_b32 %0, %1" : "+v"(w_[4]), "+v"(w_[6]));
        asm("v_permlane32_swap_b32 %0, %1" : "+v"(w_[5]), "+v"(w_[7]));

        union { u32 u[4]; bf16x8 v; } c0_, c1_;
        c0_.u[0] = w_[0]; c0_.u[1] = w_[1]; c0_.u[2] = w_[2]; c0_.u[3] = w_[3];
        c1_.u[0] = w_[4]; c1_.u[1] = w_[5]; c1_.u[2] = w_[6]; c1_.u[3] = w_[7];

        // ---- PV: O^T[d][q] += V^T[d][k] P^T[k][q] ----
        oT0 = __builtin_amdgcn_mfma_f32_32x32x16_bf16(vf[0][0], c0_.v, oT0, 0, 0, 0);
        oT0 = __builtin_amdgcn_mfma_f32_32x32x16_bf16(vf[0][1], c1_.v, oT0, 0, 0, 0);
        oT1 = __builtin_amdgcn_mfma_f32_32x32x16_bf16(vf[1][0], c0_.v, oT1, 0, 0, 0);
        oT1 = __builtin_amdgcn_mfma_f32_32x32x16_bf16(vf[1][1], c1_.v, oT1, 0, 0, 0);

#pragma unroll
        for (int c = 0; c < 4; ++c) kf[c] = kn[c];
    }

    // ---- cross-wave merge through LDS ----
    if (wave != 0) {
        sm[wave - 1][lane] = mrun;
        sl[wave - 1][lane] = lrun;
#pragma unroll
        for (int r = 0; r < 16; ++r) {
            sO[wave - 1][r][lane]      = oT0[r];
            sO[wave - 1][16 + r][lane] = oT1[r];
        }
    }
    __syncthreads();
    if (wave != 0) return;

    float M = mrun;
#pragma unroll
    for (int w = 0; w < 3; ++w) M = fmaxf(M, sm[w][lane]);
    {
        const float c0 = exp2f(mrun - M);
        lrun *= c0; oT0 *= c0; oT1 *= c0;
    }
#pragma unroll
    for (int w = 0; w < 3; ++w) {
        const float cw = exp2f(sm[w][lane] - M);
        lrun += sl[w][lane] * cw;
#pragma unroll
        for (int r = 0; r < 16; ++r) {
            oT0[r] += sO[w][r][lane] * cw;
            oT1[r] += sO[w][16 + r][lane] * cw;
        }
    }

    // ---- epilogue: O[q][d] = O^T/l -> ctx[token][h*64+d], 8B packed stores ----
    const float inv = 1.0f / lrun;
    const size_t base = ((size_t)(b * SEQ + qb + col)) * DINNER + h * 64;
#pragma unroll
    for (int g = 0; g < 4; ++g) {
        __bf16 t4[4];
#pragma unroll
        for (int j = 0; j < 4; ++j) t4[j] = (__bf16)(oT0[4 * g + j] * inv);
        *(uint2*)&ctx[base + 8 * g + 4 * hi] = *(uint2*)t4;
#pragma unroll
        for (int j = 0; j < 4; ++j) t4[j] = (__bf16)(oT1[4 * g + j] * inv);
        *(uint2*)&ctx[base + 32 + 8 * g + 4 * hi] = *(uint2*)t4;
    }
}

// ---------------------------------------------------------------------------
extern "C" void kernel_launch(void* const* d_in, const int* in_sizes, int n_in,
                              void* d_out, int out_size, void* d_ws, size_t ws_size,
                              hipStream_t stream)
{
    const float* X  = (const float*)d_in[0];
    const float* Wq = (const float*)d_in[1];
    const float* bq = (const float*)d_in[2];
    const float* Wk = (const float*)d_in[3];
    const float* bk = (const float*)d_in[4];
    const float* Wv = (const float*)d_in[5];
    const float* bv = (const float*)d_in[6];
    const float* Wo = (const float*)d_in[7];
    const float* bo = (const float*)d_in[8];
    float* out = (float*)d_out;

    // bf16 workspace layout (element offsets, 1 Mi = 1048576)
    __bf16* ws  = (__bf16*)d_ws;
    const size_t MI = 1048576;
    __bf16* Xb   = ws;               // 4 Mi  [4096][1024]
    __bf16* Wtq  = ws + 4  * MI;     // 1 Mi  [1024 n][1024 k]
    __bf16* Wtk  = ws + 5  * MI;
    __bf16* Wtv  = ws + 6  * MI;
    __bf16* Wto  = ws + 7  * MI;
    __bf16* Qb   = ws + 8  * MI;     // 4 Mi  [bh][s][d], pre-scaled 0.125*log2e
    __bf16* Kb   = ws + 12 * MI;     // 4 Mi  [bh][s][d]
    __bf16* Vtb  = ws + 16 * MI;     // 4 Mi  [bh][d][s]
    __bf16* ctxb = ws + 20 * MI;     // 4 Mi  [tok][h*64+d]

    // 1) convert input + 4 weight transposes (one launch each)
    cvt_bf16<<<dim3(MTOK * EMBED / 1024), dim3(256), 0, stream>>>(X, Xb, MTOK * EMBED);
    tconv4<<<dim3(32, 32, 4), dim3(256), 0, stream>>>(Wq, Wk, Wv, Wo, Wtq, Wtk, Wtv, Wto);

    // 2) fused QKV projection (bf16 MFMA GEMM), writes Q(scaled)/K row-major + V transposed
    {
        dim3 grid(DINNER / 128, MTOK / 128, 3), blk(256);
        gemm128<<<grid, blk, 0, stream>>>(Xb, Wtq, Wtk, Wtv, bq, bk, bv,
                                          Qb, Kb, Vtb, EMBED, 0);
    }

    // 3) causal flash attention (MFMA, 4-way k-split)
    {
        dim3 grid(32 * (SEQ / 32)), blk(256);
        attn_mfma<<<grid, blk, 0, stream>>>(Qb, Kb, Vtb, ctxb);
    }

    // 4) output projection -> fp32 d_out
    {
        dim3 grid(EMBED / 128, MTOK / 128, 1), blk(256);
        gemm128<<<grid, blk, 0, stream>>>(ctxb, Wto, Wto, Wto, bo, bo, bo,
                                          out, out, out, DINNER, 1);
    }
}

// Round 5
// 152.634 us; speedup vs baseline: 44.3760x; 1.0440x over previous
//
#include <hip/hip_runtime.h>
#include <hip/hip_bf16.h>
#include <math.h>

#define NH 16
#define DH 64
#define SEQ 2048
#define EMBED 1024
#define DINNER 1024
#define BATCH 2
#define MTOK 4096   // BATCH*SEQ

typedef __bf16 bf16x8 __attribute__((ext_vector_type(8)));
typedef float  f32x4  __attribute__((ext_vector_type(4)));
typedef float  f32x16 __attribute__((ext_vector_type(16)));
typedef unsigned int u32;

// async global->LDS, 16B per lane (dest = wave-uniform base + lane*16)
__device__ __forceinline__ void gload16(const void* g, void* l) {
    __builtin_amdgcn_global_load_lds((const __attribute__((address_space(1))) void*)g,
                                     (__attribute__((address_space(3))) void*)l, 16, 0, 0);
}

// ---------------------------------------------------------------------------
// f32 -> bf16 flat convert (n divisible by 4)
// ---------------------------------------------------------------------------
__global__ __launch_bounds__(256) void cvt_bf16(
    const float* __restrict__ src, __bf16* __restrict__ dst, int n)
{
    int i = (blockIdx.x * 256 + threadIdx.x) * 4;
    if (i + 3 < n) {
        float4 v = *(const float4*)&src[i];
        dst[i + 0] = (__bf16)v.x;
        dst[i + 1] = (__bf16)v.y;
        dst[i + 2] = (__bf16)v.z;
        dst[i + 3] = (__bf16)v.w;
    }
}

// ---------------------------------------------------------------------------
// 4 weight transposes (all 1024x1024) in one launch: src[R][C] f32 -> dst[C][R] bf16
// ---------------------------------------------------------------------------
__global__ __launch_bounds__(256) void tconv4(
    const float* __restrict__ W0, const float* __restrict__ W1,
    const float* __restrict__ W2, const float* __restrict__ W3,
    __bf16* __restrict__ D0, __bf16* __restrict__ D1,
    __bf16* __restrict__ D2, __bf16* __restrict__ D3)
{
    const int z = blockIdx.z;
    const float* __restrict__ src = (z == 0) ? W0 : (z == 1) ? W1 : (z == 2) ? W2 : W3;
    __bf16* __restrict__ dst      = (z == 0) ? D0 : (z == 1) ? D1 : (z == 2) ? D2 : D3;
    const int R = 1024, C = 1024;

    __shared__ float t[32][33];
    const int c0 = blockIdx.x * 32, r0 = blockIdx.y * 32;
    const int x = threadIdx.x & 31, y = threadIdx.x >> 5;   // 32 x 8
#pragma unroll
    for (int i = 0; i < 4; ++i)
        t[y + 8 * i][x] = src[(size_t)(r0 + y + 8 * i) * C + c0 + x];
    __syncthreads();
#pragma unroll
    for (int i = 0; i < 4; ++i)
        dst[(size_t)(c0 + y + 8 * i) * R + r0 + x] = (__bf16)t[x][y + 8 * i];
}

// ---------------------------------------------------------------------------
// bf16 MFMA GEMM, 128x128 tile, 4 waves (2x2), 16x16x32 MFMA, K-step 32.
// m97 recipe: linear [128][32] LDS staged via global_load_lds width=16.
// A[M][K] bf16, Bt[N][K] bf16 (pre-transposed weights).
// mode3=0: blockIdx.z selects Q/K/V epilogue; mode3=1: fp32 out[m][EMBED]+bias.
//   z=0 -> Q layout [bh][s][d] bf16, scaled by 0.125*log2e (exp2-domain softmax)
//   z=1 -> K layout [bh][s][d] bf16
//   z=2 -> V layout transposed [bh][d][s] bf16
// ---------------------------------------------------------------------------
#define QSCALE 0.18033688f   // 0.125 * log2(e)

__global__ __launch_bounds__(256) void gemm128(
    const __bf16* __restrict__ A,
    const __bf16* __restrict__ Bt0, const __bf16* __restrict__ Bt1, const __bf16* __restrict__ Bt2,
    const float* __restrict__ b0, const float* __restrict__ b1, const float* __restrict__ b2,
    void* __restrict__ o0, void* __restrict__ o1, void* __restrict__ o2,
    int Kdim, int mode3)
{
    const int z = blockIdx.z;
    const __bf16* __restrict__ Bt = (z == 0) ? Bt0 : (z == 1) ? Bt1 : Bt2;
    const float*  __restrict__ bias = (z == 0) ? b0 : (z == 1) ? b1 : b2;
    void* __restrict__ outp = (z == 0) ? o0 : (z == 1) ? o1 : o2;
    const int mode = mode3 ? 3 : z;
    const float scale = (mode == 0) ? QSCALE : 1.0f;

    __shared__ __bf16 As[128 * 32];
    __shared__ __bf16 Bs[128 * 32];

    const int tid  = threadIdx.x;
    const int lane = tid & 63;
    const int wid  = tid >> 6;
    const int wm = wid >> 1, wn = wid & 1;
    const int ls = lane & 15, lg = lane >> 4;
    const int m0 = blockIdx.y * 128, n0 = blockIdx.x * 128;

    const int sr = tid >> 2;           // 0..63
    const int sc = (tid & 3) * 8;      // element col offset (8 bf16 = 16B)

    f32x4 acc[4][4] = {};

    for (int k0 = 0; k0 < Kdim; k0 += 32) {
        gload16(&A [(size_t)(m0 + sr)      * Kdim + k0 + sc], &As[sr * 32 + sc]);
        gload16(&A [(size_t)(m0 + 64 + sr) * Kdim + k0 + sc], &As[(64 + sr) * 32 + sc]);
        gload16(&Bt[(size_t)(n0 + sr)      * Kdim + k0 + sc], &Bs[sr * 32 + sc]);
        gload16(&Bt[(size_t)(n0 + 64 + sr) * Kdim + k0 + sc], &Bs[(64 + sr) * 32 + sc]);
        __syncthreads();

        bf16x8 af[4], bfr[4];
#pragma unroll
        for (int i = 0; i < 4; ++i) {
            af[i]  = *(const bf16x8*)&As[(wm * 64 + i * 16 + ls) * 32 + lg * 8];
            bfr[i] = *(const bf16x8*)&Bs[(wn * 64 + i * 16 + ls) * 32 + lg * 8];
        }
#pragma unroll
        for (int i = 0; i < 4; ++i)
#pragma unroll
            for (int jx = 0; jx < 4; ++jx)
                acc[i][jx] = __builtin_amdgcn_mfma_f32_16x16x32_bf16(af[i], bfr[jx], acc[i][jx], 0, 0, 0);
        __syncthreads();
    }

    // epilogue: C/D layout col = lane&15, row = (lane>>4)*4 + j   [m89-verified]
#pragma unroll
    for (int i = 0; i < 4; ++i) {
#pragma unroll
        for (int jx = 0; jx < 4; ++jx) {
#pragma unroll
            for (int j = 0; j < 4; ++j) {
                const int m = m0 + wm * 64 + i * 16 + lg * 4 + j;
                const int n = n0 + wn * 64 + jx * 16 + ls;
                const float v = (acc[i][jx][j] + bias[n]) * scale;
                if (mode == 3) {
                    ((float*)outp)[(size_t)m * EMBED + n] = v;
                } else {
                    const int b = m >> 11, s = m & 2047;   // SEQ=2048
                    const int h = n >> 6,  d = n & 63;
                    if (mode == 2)
                        ((__bf16*)outp)[(((size_t)(b * NH + h) * DH + d) << 11) + s] = (__bf16)v;
                    else
                        ((__bf16*)outp)[((((size_t)(b * NH + h) << 11) + s) * DH) + d] = (__bf16)v;
                }
            }
        }
    }
}

// ---------------------------------------------------------------------------
// MFMA causal flash attention, LDS-staged K/V shared across 4 waves.
// Block = 256 threads = 4 waves, Q tile = 128 rows (wave w owns rows qb+w*32..+31).
// Per 64-key tile: coalesced global_load_lds stage of K[64][64] and V^T[64][64]
// (double-buffered, XOR-swizzled rows: byte ^= ((row&7)<<4), pre-swizzled on the
// global source per rule #21), then each wave runs two 32-key subtiles:
// swapped QK^T (S^T = K@Q^T), in-register exp2 softmax with defer-max (T13),
// P->bf16 via v_cvt_pk_bf16_f32 + v_permlane32_swap_b32 (T12), PV from LDS V^T.
// Q,K: [bh][s][d] bf16 (Q pre-scaled 0.125*log2e). Vt: [bh][d][s] bf16.
// ctx: bf16 [b*SEQ+s][h*64+d].
// ---------------------------------------------------------------------------
__global__ __launch_bounds__(256) void attn_mfma(
    const __bf16* __restrict__ Q, const __bf16* __restrict__ K,
    const __bf16* __restrict__ Vt, __bf16* __restrict__ ctx)
{
    // per buffer: [0,4096) K-tile 64 rows x 128B, [4096,8192) V^T-tile 64 rows x 128B
    __shared__ __bf16 lds[2][8192];

    const int tid  = threadIdx.x;
    const int wave = tid >> 6;
    const int lane = tid & 63;
    const int col  = lane & 31;          // q column / fragment row index
    const int hi   = lane >> 5;
    const int bh  = blockIdx.x & 31;     // consecutive blocks spread bh across XCDs
    const int qtb = 15 - (blockIdx.x >> 5);  // reversed: long blocks first
    const int qb  = qtb * 128;
    const int qlo = qb + wave * 32;      // this wave's 32 q rows
    const int b = bh >> 4, h = bh & 15;

    const __bf16* __restrict__ Qb = Q + ((size_t)bh << 11) * DH;
    const char* __restrict__ Kg = (const char*)(K  + ((size_t)bh << 11) * DH);
    const char* __restrict__ Vg = (const char*)(Vt + ((size_t)bh << 11) * DH);

    // staging constants: thread loads 16B at tile-linear byte o = i*4096 + tid*16;
    // row = o>>7, col-byte = o&127; source pre-swizzled by ((row&7)<<4)
    const int srow = tid >> 3;                 // 0..31
    const int scb  = (tid & 7) * 16;           // 0..112
    const int sswz = scb ^ ((srow & 7) << 4);  // (i*32 preserves row&7)

    // Q B-frags (col = q, k-dim = d), once per block
    bf16x8 qf[4];
#pragma unroll
    for (int c = 0; c < 4; ++c)
        qf[c] = *(const bf16x8*)&Qb[(size_t)(qlo + col) * DH + c * 16 + hi * 8];

    const int nt = 2 * qtb + 2;          // number of 64-key tiles for this block

    // prologue: stage tile 0 into buf 0
#pragma unroll
    for (int i = 0; i < 2; ++i) {
        const int row = i * 32 + srow;
        gload16(Kg + (size_t)row * 128 + sswz,
                (char*)&lds[0][0] + i * 4096 + tid * 16);
        gload16(Vg + (size_t)row * 4096 + sswz,
                (char*)&lds[0][4096] + i * 4096 + tid * 16);
    }
    __syncthreads();

    f32x16 oT0 = {}, oT1 = {};           // O^T[d][q], d-halves 0-31 / 32-63
    float mrun = -INFINITY, lrun = 0.f;
    int cur = 0;
    const int swz = (col & 7) << 4;

    for (int t = 0; t < nt; ++t) {
        // stage next tile into the other buffer (latency hides under compute)
        if (t + 1 < nt) {
            const int kbn = (t + 1) * 64;
#pragma unroll
            for (int i = 0; i < 2; ++i) {
                const int row = i * 32 + srow;
                gload16(Kg + (size_t)(kbn + row) * 128 + sswz,
                        (char*)&lds[cur ^ 1][0] + i * 4096 + tid * 16);
                gload16(Vg + (size_t)row * 4096 + (size_t)kbn * 2 + sswz,
                        (char*)&lds[cur ^ 1][4096] + i * 4096 + tid * 16);
            }
        }

        const int kb = t * 64;
        const char* ldsK = (const char*)&lds[cur][0];
        const char* ldsV = (const char*)&lds[cur][4096];

#pragma unroll
        for (int sub = 0; sub < 2; ++sub) {
            const int k0 = kb + sub * 32;
            if (k0 > qlo + 31) break;    // wave-uniform; later tiles: stage+barrier only

            // ---- K fragments from LDS (swizzled read) ----
            bf16x8 kf[4];
            const int krow = sub * 32 + col;
#pragma unroll
            for (int c = 0; c < 4; ++c)
                kf[c] = *(const bf16x8*)(ldsK + krow * 128 + ((c * 32 + hi * 16) ^ swz));

            // ---- QK^T: S^T[32k][32q] ----
            f32x16 st = {};
#pragma unroll
            for (int c = 0; c < 4; ++c)
                st = __builtin_amdgcn_mfma_f32_32x32x16_bf16(kf[c], qf[c], st, 0, 0, 0);

            // ---- causal mask (only on diagonal-crossing subtiles) ----
            if (k0 + 31 > qlo) {
#pragma unroll
                for (int r = 0; r < 16; ++r) {
                    const int krel = (r & 3) + 8 * (r >> 2) + 4 * hi;
                    if (k0 + krel > qlo + col) st[r] = -INFINITY;
                }
            }

            // ---- online softmax (exp2 domain), defer-max rescale ----
            float t0 = fmaxf(fmaxf(fmaxf(st[0], st[1]), fmaxf(st[2], st[3])),
                             fmaxf(fmaxf(st[4], st[5]), fmaxf(st[6], st[7])));
            float t1 = fmaxf(fmaxf(fmaxf(st[8], st[9]),  fmaxf(st[10], st[11])),
                             fmaxf(fmaxf(st[12], st[13]), fmaxf(st[14], st[15])));
            float tmax = fmaxf(t0, t1);
            tmax = fmaxf(tmax, __shfl_xor(tmax, 32));

            if (__any(tmax > mrun + 8.f)) {
                const float mnew = fmaxf(mrun, tmax);
                const float corr = exp2f(mrun - mnew);
                lrun *= corr;
                oT0 *= corr;
                oT1 *= corr;
                mrun = mnew;
            }

            float p[16];
#pragma unroll
            for (int r = 0; r < 16; ++r) p[r] = exp2f(st[r] - mrun);
            float ps0 = ((p[0] + p[1]) + (p[2] + p[3])) + ((p[4] + p[5]) + (p[6] + p[7]));
            float ps1 = ((p[8] + p[9]) + (p[10] + p[11])) + ((p[12] + p[13]) + (p[14] + p[15]));
            float psum = ps0 + ps1;
            psum += __shfl_xor(psum, 32);
            lrun += psum;

            // ---- pack P -> bf16 B-frags (cvt_pk + permlane32_swap) ----
            u32 w_[8];
#pragma unroll
            for (int i = 0; i < 8; ++i) {
                u32 r_;
                asm("v_cvt_pk_bf16_f32 %0, %1, %2" : "=v"(r_) : "v"(p[2 * i]), "v"(p[2 * i + 1]));
                w_[i] = r_;
            }
            asm("v_permlane32_swap_b32 %0, %1" : "+v"(w_[0]), "+v"(w_[2]));
            asm("v_permlane32_swap_b32 %0, %1" : "+v"(w_[1]), "+v"(w_[3]));
            asm("v_permlane32_swap_b32 %0, %1" : "+v"(w_[4]), "+v"(w_[6]));
            asm("v_permlane32_swap_b32 %0, %1" : "+v"(w_[5]), "+v"(w_[7]));

            union { u32 u[4]; bf16x8 v; } c0_, c1_;
            c0_.u[0] = w_[0]; c0_.u[1] = w_[1]; c0_.u[2] = w_[2]; c0_.u[3] = w_[3];
            c1_.u[0] = w_[4]; c1_.u[1] = w_[5]; c1_.u[2] = w_[6]; c1_.u[3] = w_[7];

            // ---- PV from LDS V^T (swizzled read): O^T += V^T[d][k] P^T[k][q] ----
            const int s0b = (sub * 2) * 32;      // byte col of first 16-k slice
            bf16x8 v00 = *(const bf16x8*)(ldsV + (     col) * 128 + ((s0b      + hi * 16) ^ swz));
            bf16x8 v01 = *(const bf16x8*)(ldsV + (     col) * 128 + ((s0b + 32 + hi * 16) ^ swz));
            bf16x8 v10 = *(const bf16x8*)(ldsV + (32 + col) * 128 + ((s0b      + hi * 16) ^ swz));
            bf16x8 v11 = *(const bf16x8*)(ldsV + (32 + col) * 128 + ((s0b + 32 + hi * 16) ^ swz));
            oT0 = __builtin_amdgcn_mfma_f32_32x32x16_bf16(v00, c0_.v, oT0, 0, 0, 0);
            oT0 = __builtin_amdgcn_mfma_f32_32x32x16_bf16(v01, c1_.v, oT0, 0, 0, 0);
            oT1 = __builtin_amdgcn_mfma_f32_32x32x16_bf16(v10, c0_.v, oT1, 0, 0, 0);
            oT1 = __builtin_amdgcn_mfma_f32_32x32x16_bf16(v11, c1_.v, oT1, 0, 0, 0);
        }

        __syncthreads();    // also drains next-tile stage (vmcnt) per barrier semantics
        cur ^= 1;
    }

    // ---- epilogue: O[q][d] = O^T/l -> ctx[token][h*64+d], 8B packed stores ----
    const float inv = 1.0f / lrun;
    const size_t base = ((size_t)(b * SEQ + qlo + col)) * DINNER + h * 64;
#pragma unroll
    for (int g = 0; g < 4; ++g) {
        __bf16 t4[4];
#pragma unroll
        for (int j = 0; j < 4; ++j) t4[j] = (__bf16)(oT0[4 * g + j] * inv);
        *(uint2*)&ctx[base + 8 * g + 4 * hi] = *(uint2*)t4;
#pragma unroll
        for (int j = 0; j < 4; ++j) t4[j] = (__bf16)(oT1[4 * g + j] * inv);
        *(uint2*)&ctx[base + 32 + 8 * g + 4 * hi] = *(uint2*)t4;
    }
}

// ---------------------------------------------------------------------------
extern "C" void kernel_launch(void* const* d_in, const int* in_sizes, int n_in,
                              void* d_out, int out_size, void* d_ws, size_t ws_size,
                              hipStream_t stream)
{
    const float* X  = (const float*)d_in[0];
    const float* Wq = (const float*)d_in[1];
    const float* bq = (const float*)d_in[2];
    const float* Wk = (const float*)d_in[3];
    const float* bk = (const float*)d_in[4];
    const float* Wv = (const float*)d_in[5];
    const float* bv = (const float*)d_in[6];
    const float* Wo = (const float*)d_in[7];
    const float* bo = (const float*)d_in[8];
    float* out = (float*)d_out;

    // bf16 workspace layout (element offsets, 1 Mi = 1048576)
    __bf16* ws  = (__bf16*)d_ws;
    const size_t MI = 1048576;
    __bf16* Xb   = ws;               // 4 Mi  [4096][1024]
    __bf16* Wtq  = ws + 4  * MI;     // 1 Mi  [1024 n][1024 k]
    __bf16* Wtk  = ws + 5  * MI;
    __bf16* Wtv  = ws + 6  * MI;
    __bf16* Wto  = ws + 7  * MI;
    __bf16* Qb   = ws + 8  * MI;     // 4 Mi  [bh][s][d], pre-scaled 0.125*log2e
    __bf16* Kb   = ws + 12 * MI;     // 4 Mi  [bh][s][d]
    __bf16* Vtb  = ws + 16 * MI;     // 4 Mi  [bh][d][s]
    __bf16* ctxb = ws + 20 * MI;     // 4 Mi  [tok][h*64+d]

    // 1) convert input + 4 weight transposes
    cvt_bf16<<<dim3(MTOK * EMBED / 1024), dim3(256), 0, stream>>>(X, Xb, MTOK * EMBED);
    tconv4<<<dim3(32, 32, 4), dim3(256), 0, stream>>>(Wq, Wk, Wv, Wo, Wtq, Wtk, Wtv, Wto);

    // 2) fused QKV projection (bf16 MFMA GEMM), writes Q(scaled)/K row-major + V transposed
    {
        dim3 grid(DINNER / 128, MTOK / 128, 3), blk(256);
        gemm128<<<grid, blk, 0, stream>>>(Xb, Wtq, Wtk, Wtv, bq, bk, bv,
                                          Qb, Kb, Vtb, EMBED, 0);
    }

    // 3) causal flash attention (MFMA, LDS-staged shared K/V, 128-row Q tiles)
    {
        dim3 grid(32 * (SEQ / 128)), blk(256);
        attn_mfma<<<grid, blk, 0, stream>>>(Qb, Kb, Vtb, ctxb);
    }

    // 4) output projection -> fp32 d_out
    {
        dim3 grid(EMBED / 128, MTOK / 128, 1), blk(256);
        gemm128<<<grid, blk, 0, stream>>>(ctxb, Wto, Wto, Wto, bo, bo, bo,
                                          out, out, out, DINNER, 1);
    }
}

// Round 6
// 150.274 us; speedup vs baseline: 45.0732x; 1.0157x over previous
//
#include <hip/hip_runtime.h>
#include <hip/hip_bf16.h>
#include <math.h>

#define NH 16
#define DH 64
#define SEQ 2048
#define EMBED 1024
#define DINNER 1024
#define BATCH 2
#define MTOK 4096   // BATCH*SEQ

typedef __bf16 bf16x8 __attribute__((ext_vector_type(8)));
typedef float  f32x4  __attribute__((ext_vector_type(4)));
typedef float  f32x16 __attribute__((ext_vector_type(16)));
typedef unsigned int u32;

// async global->LDS, 16B per lane (dest = wave-uniform base + lane*16)
__device__ __forceinline__ void gload16(const void* g, void* l) {
    __builtin_amdgcn_global_load_lds((const __attribute__((address_space(1))) void*)g,
                                     (__attribute__((address_space(3))) void*)l, 16, 0, 0);
}

// ---------------------------------------------------------------------------
// f32 -> bf16 flat convert (n divisible by 4)
// ---------------------------------------------------------------------------
__global__ __launch_bounds__(256) void cvt_bf16(
    const float* __restrict__ src, __bf16* __restrict__ dst, int n)
{
    int i = (blockIdx.x * 256 + threadIdx.x) * 4;
    if (i + 3 < n) {
        float4 v = *(const float4*)&src[i];
        dst[i + 0] = (__bf16)v.x;
        dst[i + 1] = (__bf16)v.y;
        dst[i + 2] = (__bf16)v.z;
        dst[i + 3] = (__bf16)v.w;
    }
}

// ---------------------------------------------------------------------------
// 4 weight transposes (all 1024x1024) in one launch: src[R][C] f32 -> dst[C][R] bf16
// ---------------------------------------------------------------------------
__global__ __launch_bounds__(256) void tconv4(
    const float* __restrict__ W0, const float* __restrict__ W1,
    const float* __restrict__ W2, const float* __restrict__ W3,
    __bf16* __restrict__ D0, __bf16* __restrict__ D1,
    __bf16* __restrict__ D2, __bf16* __restrict__ D3)
{
    const int z = blockIdx.z;
    const float* __restrict__ src = (z == 0) ? W0 : (z == 1) ? W1 : (z == 2) ? W2 : W3;
    __bf16* __restrict__ dst      = (z == 0) ? D0 : (z == 1) ? D1 : (z == 2) ? D2 : D3;
    const int R = 1024, C = 1024;

    __shared__ float t[32][33];
    const int c0 = blockIdx.x * 32, r0 = blockIdx.y * 32;
    const int x = threadIdx.x & 31, y = threadIdx.x >> 5;   // 32 x 8
#pragma unroll
    for (int i = 0; i < 4; ++i)
        t[y + 8 * i][x] = src[(size_t)(r0 + y + 8 * i) * C + c0 + x];
    __syncthreads();
#pragma unroll
    for (int i = 0; i < 4; ++i)
        dst[(size_t)(c0 + y + 8 * i) * R + r0 + x] = (__bf16)t[x][y + 8 * i];
}

// ---------------------------------------------------------------------------
// bf16 MFMA GEMM, 128x128 tile, 4 waves (2x2), 16x16x32 MFMA, K-step 32.
// m97 recipe: linear [128][32] LDS staged via global_load_lds width=16.
// A[M][K] bf16, Bt[N][K] bf16 (pre-transposed weights).
// mode3=0: blockIdx.z selects Q/K/V epilogue; mode3=1: fp32 out[m][EMBED]+bias.
//   z=0 -> Q layout [bh][s][d] bf16, scaled by 0.125*log2e (exp2-domain softmax)
//   z=1 -> K layout [bh][s][d] bf16
//   z=2 -> V layout transposed [bh][d][s] bf16
// ---------------------------------------------------------------------------
#define QSCALE 0.18033688f   // 0.125 * log2(e)

__global__ __launch_bounds__(256) void gemm128(
    const __bf16* __restrict__ A,
    const __bf16* __restrict__ Bt0, const __bf16* __restrict__ Bt1, const __bf16* __restrict__ Bt2,
    const float* __restrict__ b0, const float* __restrict__ b1, const float* __restrict__ b2,
    void* __restrict__ o0, void* __restrict__ o1, void* __restrict__ o2,
    int Kdim, int mode3)
{
    const int z = blockIdx.z;
    const __bf16* __restrict__ Bt = (z == 0) ? Bt0 : (z == 1) ? Bt1 : Bt2;
    const float*  __restrict__ bias = (z == 0) ? b0 : (z == 1) ? b1 : b2;
    void* __restrict__ outp = (z == 0) ? o0 : (z == 1) ? o1 : o2;
    const int mode = mode3 ? 3 : z;
    const float scale = (mode == 0) ? QSCALE : 1.0f;

    __shared__ __bf16 As[128 * 32];
    __shared__ __bf16 Bs[128 * 32];

    const int tid  = threadIdx.x;
    const int lane = tid & 63;
    const int wid  = tid >> 6;
    const int wm = wid >> 1, wn = wid & 1;
    const int ls = lane & 15, lg = lane >> 4;
    const int m0 = blockIdx.y * 128, n0 = blockIdx.x * 128;

    const int sr = tid >> 2;           // 0..63
    const int sc = (tid & 3) * 8;      // element col offset (8 bf16 = 16B)

    f32x4 acc[4][4] = {};

    for (int k0 = 0; k0 < Kdim; k0 += 32) {
        gload16(&A [(size_t)(m0 + sr)      * Kdim + k0 + sc], &As[sr * 32 + sc]);
        gload16(&A [(size_t)(m0 + 64 + sr) * Kdim + k0 + sc], &As[(64 + sr) * 32 + sc]);
        gload16(&Bt[(size_t)(n0 + sr)      * Kdim + k0 + sc], &Bs[sr * 32 + sc]);
        gload16(&Bt[(size_t)(n0 + 64 + sr) * Kdim + k0 + sc], &Bs[(64 + sr) * 32 + sc]);
        __syncthreads();

        bf16x8 af[4], bfr[4];
#pragma unroll
        for (int i = 0; i < 4; ++i) {
            af[i]  = *(const bf16x8*)&As[(wm * 64 + i * 16 + ls) * 32 + lg * 8];
            bfr[i] = *(const bf16x8*)&Bs[(wn * 64 + i * 16 + ls) * 32 + lg * 8];
        }
#pragma unroll
        for (int i = 0; i < 4; ++i)
#pragma unroll
            for (int jx = 0; jx < 4; ++jx)
                acc[i][jx] = __builtin_amdgcn_mfma_f32_16x16x32_bf16(af[i], bfr[jx], acc[i][jx], 0, 0, 0);
        __syncthreads();
    }

    // epilogue: C/D layout col = lane&15, row = (lane>>4)*4 + j   [m89-verified]
#pragma unroll
    for (int i = 0; i < 4; ++i) {
#pragma unroll
        for (int jx = 0; jx < 4; ++jx) {
#pragma unroll
            for (int j = 0; j < 4; ++j) {
                const int m = m0 + wm * 64 + i * 16 + lg * 4 + j;
                const int n = n0 + wn * 64 + jx * 16 + ls;
                const float v = (acc[i][jx][j] + bias[n]) * scale;
                if (mode == 3) {
                    ((float*)outp)[(size_t)m * EMBED + n] = v;
                } else {
                    const int b = m >> 11, s = m & 2047;   // SEQ=2048
                    const int h = n >> 6,  d = n & 63;
                    if (mode == 2)
                        ((__bf16*)outp)[(((size_t)(b * NH + h) * DH + d) << 11) + s] = (__bf16)v;
                    else
                        ((__bf16*)outp)[((((size_t)(b * NH + h) << 11) + s) * DH) + d] = (__bf16)v;
                }
            }
        }
    }
}

// ---------------------------------------------------------------------------
// MFMA causal flash attention. Block = 128 threads = 2 waves, Q tile = 64 rows
// (wave w owns rows qb+w*32..+31). Grid = 32 bh x 32 q-tiles = 1024 blocks,
// long-first; same-bh blocks land on one XCD (index stride 32) -> K/V L2-hot.
// Per 64-key tile: coalesced global_load_lds stage of K[64][128B] and
// V^T[64][128B] (double-buffered, XOR-swizzled rows byte^=((row&7)<<4),
// pre-swizzled global source per rule #21). Each wave then does ONE 64-key
// softmax pass: two swapped QK^T subtiles (S^T = K@Q^T), merged fmax/psum
// trees (+1 shfl each), defer-max (T13), exp2 domain, P->bf16 via
// v_cvt_pk_bf16_f32 + v_permlane32_swap_b32 (T12), PV from LDS V^T.
// Q,K: [bh][s][d] bf16 (Q pre-scaled 0.125*log2e). Vt: [bh][d][s] bf16.
// ctx: bf16 [b*SEQ+s][h*64+d].
// ---------------------------------------------------------------------------
__global__ __launch_bounds__(128) void attn_mfma(
    const __bf16* __restrict__ Q, const __bf16* __restrict__ K,
    const __bf16* __restrict__ Vt, __bf16* __restrict__ ctx)
{
    // per buffer: bytes [0,8192) = K tile, [8192,16384) = V^T tile
    __shared__ __bf16 lds[2][8192];

    const int tid  = threadIdx.x;        // 0..127
    const int wave = tid >> 6;           // 0..1
    const int lane = tid & 63;
    const int col  = lane & 31;          // q column / fragment row index
    const int hi   = lane >> 5;
    const int bh = blockIdx.x & 31;      // same-bh blocks stride 32 -> same XCD
    const int qt = 31 - (blockIdx.x >> 5);  // reversed: long blocks first
    const int qb  = qt * 64;
    const int qlo = qb + wave * 32;      // this wave's 32 q rows
    const int b = bh >> 4, h = bh & 15;

    const __bf16* __restrict__ Qb = Q + ((size_t)bh << 11) * DH;
    const char* __restrict__ Kg = (const char*)(K  + ((size_t)bh << 11) * DH);
    const char* __restrict__ Vg = (const char*)(Vt + ((size_t)bh << 11) * DH);

    // staging: thread loads 16B at tile-linear byte o = i*2048 + tid*16;
    // row = o>>7 = i*16 + (tid>>3); source pre-swizzled by ((row&7)<<4)
    const int srow = tid >> 3;                 // 0..15
    const int sswz = ((tid & 7) * 16) ^ ((srow & 7) << 4);   // i*16 preserves row&7

    // Q B-frags (col = q, k-dim = d)
    bf16x8 qf[4];
#pragma unroll
    for (int c = 0; c < 4; ++c)
        qf[c] = *(const bf16x8*)&Qb[(size_t)(qlo + col) * DH + c * 16 + hi * 8];

    const int nt = qt + 1;               // 64-key tiles for this block

    // prologue: stage tile 0 into buf 0
#pragma unroll
    for (int i = 0; i < 4; ++i) {
        const int row = i * 16 + srow;
        gload16(Kg + (size_t)row * 128 + sswz,
                (char*)&lds[0][0] + i * 2048 + tid * 16);
        gload16(Vg + (size_t)row * 4096 + sswz,
                (char*)&lds[0][0] + 8192 + i * 2048 + tid * 16);
    }
    __syncthreads();

    f32x16 oT0 = {}, oT1 = {};           // O^T[d][q], d-halves 0-31 / 32-63
    float mrun = -INFINITY, lrun = 0.f;
    int cur = 0;
    const int swz = (col & 7) << 4;

    for (int t = 0; t < nt; ++t) {
        // stage next tile into the other buffer (hides under compute)
        if (t + 1 < nt) {
            const int kbn = (t + 1) * 64;
#pragma unroll
            for (int i = 0; i < 4; ++i) {
                const int row = i * 16 + srow;
                gload16(Kg + (size_t)(kbn + row) * 128 + sswz,
                        (char*)&lds[cur ^ 1][0] + i * 2048 + tid * 16);
                gload16(Vg + (size_t)row * 4096 + (size_t)kbn * 2 + sswz,
                        (char*)&lds[cur ^ 1][0] + 8192 + i * 2048 + tid * 16);
            }
        }

        const int k0 = t * 64;
        const char* ldsK = (const char*)&lds[cur][0];
        const char* ldsV = ldsK + 8192;

        // ---- K fragments for both 32-key subtiles (swizzled LDS read) ----
        bf16x8 kfa[4], kfb[4];
#pragma unroll
        for (int c = 0; c < 4; ++c) {
            kfa[c] = *(const bf16x8*)(ldsK + (     col) * 128 + ((c * 32 + hi * 16) ^ swz));
            kfb[c] = *(const bf16x8*)(ldsK + (32 + col) * 128 + ((c * 32 + hi * 16) ^ swz));
        }

        // ---- QK^T: two independent S^T[32k][32q] chains ----
        f32x16 sta = {}, stb = {};
#pragma unroll
        for (int c = 0; c < 4; ++c) {
            sta = __builtin_amdgcn_mfma_f32_32x32x16_bf16(kfa[c], qf[c], sta, 0, 0, 0);
            stb = __builtin_amdgcn_mfma_f32_32x32x16_bf16(kfb[c], qf[c], stb, 0, 0, 0);
        }

        // ---- causal mask (diagonal-crossing tiles only) ----
        if (k0 + 63 > qlo) {
#pragma unroll
            for (int r = 0; r < 16; ++r) {
                const int krel = (r & 3) + 8 * (r >> 2) + 4 * hi;
                if (k0 + krel > qlo + col)      sta[r] = -INFINITY;
                if (k0 + 32 + krel > qlo + col) stb[r] = -INFINITY;
            }
        }

        // ---- merged 64-key online softmax (exp2 domain), defer-max ----
        float ta = fmaxf(fmaxf(fmaxf(sta[0], sta[1]), fmaxf(sta[2], sta[3])),
                         fmaxf(fmaxf(sta[4], sta[5]), fmaxf(sta[6], sta[7])));
        float tb = fmaxf(fmaxf(fmaxf(sta[8], sta[9]),  fmaxf(sta[10], sta[11])),
                         fmaxf(fmaxf(sta[12], sta[13]), fmaxf(sta[14], sta[15])));
        float tc = fmaxf(fmaxf(fmaxf(stb[0], stb[1]), fmaxf(stb[2], stb[3])),
                         fmaxf(fmaxf(stb[4], stb[5]), fmaxf(stb[6], stb[7])));
        float td = fmaxf(fmaxf(fmaxf(stb[8], stb[9]),  fmaxf(stb[10], stb[11])),
                         fmaxf(fmaxf(stb[12], stb[13]), fmaxf(stb[14], stb[15])));
        float tmax = fmaxf(fmaxf(ta, tb), fmaxf(tc, td));
        tmax = fmaxf(tmax, __shfl_xor(tmax, 32));

        if (__any(tmax > mrun + 8.f)) {
            const float mnew = fmaxf(mrun, tmax);
            const float corr = exp2f(mrun - mnew);
            lrun *= corr;
            oT0 *= corr;
            oT1 *= corr;
            mrun = mnew;
        }

        float pa[16], pb[16];
#pragma unroll
        for (int r = 0; r < 16; ++r) { pa[r] = exp2f(sta[r] - mrun); pb[r] = exp2f(stb[r] - mrun); }
        float psa = (((pa[0] + pa[1]) + (pa[2] + pa[3])) + ((pa[4] + pa[5]) + (pa[6] + pa[7])))
                  + (((pa[8] + pa[9]) + (pa[10] + pa[11])) + ((pa[12] + pa[13]) + (pa[14] + pa[15])));
        float psb = (((pb[0] + pb[1]) + (pb[2] + pb[3])) + ((pb[4] + pb[5]) + (pb[6] + pb[7])))
                  + (((pb[8] + pb[9]) + (pb[10] + pb[11])) + ((pb[12] + pb[13]) + (pb[14] + pb[15])));
        float psum = psa + psb;
        psum += __shfl_xor(psum, 32);
        lrun += psum;

        // ---- pack P -> bf16 B-frags (cvt_pk + permlane32_swap), per subtile ----
        u32 wa[8], wb[8];
#pragma unroll
        for (int i = 0; i < 8; ++i) {
            u32 r1, r2;
            asm("v_cvt_pk_bf16_f32 %0, %1, %2" : "=v"(r1) : "v"(pa[2 * i]), "v"(pa[2 * i + 1]));
            asm("v_cvt_pk_bf16_f32 %0, %1, %2" : "=v"(r2) : "v"(pb[2 * i]), "v"(pb[2 * i + 1]));
            wa[i] = r1; wb[i] = r2;
        }
        asm("v_permlane32_swap_b32 %0, %1" : "+v"(wa[0]), "+v"(wa[2]));
        asm("v_permlane32_swap_b32 %0, %1" : "+v"(wa[1]), "+v"(wa[3]));
        asm("v_permlane32_swap_b32 %0, %1" : "+v"(wa[4]), "+v"(wa[6]));
        asm("v_permlane32_swap_b32 %0, %1" : "+v"(wa[5]), "+v"(wa[7]));
        asm("v_permlane32_swap_b32 %0, %1" : "+v"(wb[0]), "+v"(wb[2]));
        asm("v_permlane32_swap_b32 %0, %1" : "+v"(wb[1]), "+v"(wb[3]));
        asm("v_permlane32_swap_b32 %0, %1" : "+v"(wb[4]), "+v"(wb[6]));
        asm("v_permlane32_swap_b32 %0, %1" : "+v"(wb[5]), "+v"(wb[7]));

        union { u32 u[4]; bf16x8 v; } cA0, cA1, cB0, cB1;
        cA0.u[0] = wa[0]; cA0.u[1] = wa[1]; cA0.u[2] = wa[2]; cA0.u[3] = wa[3];
        cA1.u[0] = wa[4]; cA1.u[1] = wa[5]; cA1.u[2] = wa[6]; cA1.u[3] = wa[7];
        cB0.u[0] = wb[0]; cB0.u[1] = wb[1]; cB0.u[2] = wb[2]; cB0.u[3] = wb[3];
        cB1.u[0] = wb[4]; cB1.u[1] = wb[5]; cB1.u[2] = wb[6]; cB1.u[3] = wb[7];

        // ---- PV from LDS V^T (swizzled read): O^T += V^T[d][k] P^T[k][q] ----
#pragma unroll
        for (int dh = 0; dh < 2; ++dh) {
            bf16x8 v0 = *(const bf16x8*)(ldsV + (dh * 32 + col) * 128 + ((0  + hi * 16) ^ swz));
            bf16x8 v1 = *(const bf16x8*)(ldsV + (dh * 32 + col) * 128 + ((32 + hi * 16) ^ swz));
            bf16x8 v2 = *(const bf16x8*)(ldsV + (dh * 32 + col) * 128 + ((64 + hi * 16) ^ swz));
            bf16x8 v3 = *(const bf16x8*)(ldsV + (dh * 32 + col) * 128 + ((96 + hi * 16) ^ swz));
            f32x16& o = dh ? oT1 : oT0;
            o = __builtin_amdgcn_mfma_f32_32x32x16_bf16(v0, cA0.v, o, 0, 0, 0);
            o = __builtin_amdgcn_mfma_f32_32x32x16_bf16(v1, cA1.v, o, 0, 0, 0);
            o = __builtin_amdgcn_mfma_f32_32x32x16_bf16(v2, cB0.v, o, 0, 0, 0);
            o = __builtin_amdgcn_mfma_f32_32x32x16_bf16(v3, cB1.v, o, 0, 0, 0);
        }

        __syncthreads();    // drains next-tile stage (vmcnt) per barrier semantics
        cur ^= 1;
    }

    // ---- epilogue: O[q][d] = O^T/l -> ctx[token][h*64+d], 8B packed stores ----
    const float inv = 1.0f / lrun;
    const size_t base = ((size_t)(b * SEQ + qlo + col)) * DINNER + h * 64;
#pragma unroll
    for (int g = 0; g < 4; ++g) {
        __bf16 t4[4];
#pragma unroll
        for (int j = 0; j < 4; ++j) t4[j] = (__bf16)(oT0[4 * g + j] * inv);
        *(uint2*)&ctx[base + 8 * g + 4 * hi] = *(uint2*)t4;
#pragma unroll
        for (int j = 0; j < 4; ++j) t4[j] = (__bf16)(oT1[4 * g + j] * inv);
        *(uint2*)&ctx[base + 32 + 8 * g + 4 * hi] = *(uint2*)t4;
    }
}

// ---------------------------------------------------------------------------
extern "C" void kernel_launch(void* const* d_in, const int* in_sizes, int n_in,
                              void* d_out, int out_size, void* d_ws, size_t ws_size,
                              hipStream_t stream)
{
    const float* X  = (const float*)d_in[0];
    const float* Wq = (const float*)d_in[1];
    const float* bq = (const float*)d_in[2];
    const float* Wk = (const float*)d_in[3];
    const float* bk = (const float*)d_in[4];
    const float* Wv = (const float*)d_in[5];
    const float* bv = (const float*)d_in[6];
    const float* Wo = (const float*)d_in[7];
    const float* bo = (const float*)d_in[8];
    float* out = (float*)d_out;

    // bf16 workspace layout (element offsets, 1 Mi = 1048576)
    __bf16* ws  = (__bf16*)d_ws;
    const size_t MI = 1048576;
    __bf16* Xb   = ws;               // 4 Mi  [4096][1024]
    __bf16* Wtq  = ws + 4  * MI;     // 1 Mi  [1024 n][1024 k]
    __bf16* Wtk  = ws + 5  * MI;
    __bf16* Wtv  = ws + 6  * MI;
    __bf16* Wto  = ws + 7  * MI;
    __bf16* Qb   = ws + 8  * MI;     // 4 Mi  [bh][s][d], pre-scaled 0.125*log2e
    __bf16* Kb   = ws + 12 * MI;     // 4 Mi  [bh][s][d]
    __bf16* Vtb  = ws + 16 * MI;     // 4 Mi  [bh][d][s]
    __bf16* ctxb = ws + 20 * MI;     // 4 Mi  [tok][h*64+d]

    // 1) convert input + 4 weight transposes
    cvt_bf16<<<dim3(MTOK * EMBED / 1024), dim3(256), 0, stream>>>(X, Xb, MTOK * EMBED);
    tconv4<<<dim3(32, 32, 4), dim3(256), 0, stream>>>(Wq, Wk, Wv, Wo, Wtq, Wtk, Wtv, Wto);

    // 2) fused QKV projection (bf16 MFMA GEMM), writes Q(scaled)/K row-major + V transposed
    {
        dim3 grid(DINNER / 128, MTOK / 128, 3), blk(256);
        gemm128<<<grid, blk, 0, stream>>>(Xb, Wtq, Wtk, Wtv, bq, bk, bv,
                                          Qb, Kb, Vtb, EMBED, 0);
    }

    // 3) causal flash attention (MFMA, 64-row Q tiles, 2 waves, 64-key LDS tiles)
    {
        dim3 grid(32 * (SEQ / 64)), blk(128);
        attn_mfma<<<grid, blk, 0, stream>>>(Qb, Kb, Vtb, ctxb);
    }

    // 4) output projection -> fp32 d_out
    {
        dim3 grid(EMBED / 128, MTOK / 128, 1), blk(256);
        gemm128<<<grid, blk, 0, stream>>>(ctxb, Wto, Wto, Wto, bo, bo, bo,
                                          out, out, out, DINNER, 1);
    }
}